// Round 2
// baseline (3166.937 us; speedup 1.0000x reference)
//
#include <hip/hip_runtime.h>
#include <math.h>

static constexpr int FEAT = 1024;
static constexpr int WDIM = 512;
static constexpr size_t PL = (size_t)FEAT * WDIM;      // 524288 per (b,c) plane
static constexpr size_t NB = (size_t)2 * 12 * PL;      // 12582912 full tensor

// ---------------- embed: 1x1 conv 3->12 ----------------
__global__ __launch_bounds__(256)
void k_embed(const float* __restrict__ x, const float* __restrict__ ew,
             const float* __restrict__ eb, float* __restrict__ h0)
{
  int t = blockIdx.x * 256 + threadIdx.x;      // 2*1024*128
  int x4 = (t & 127) * 4;
  int y  = (t >> 7) & 1023;
  int b  = t >> 17;
  float4 xi0 = *(const float4*)&x[(((size_t)b*3+0)*FEAT + y)*WDIM + x4];
  float4 xi1 = *(const float4*)&x[(((size_t)b*3+1)*FEAT + y)*WDIM + x4];
  float4 xi2 = *(const float4*)&x[(((size_t)b*3+2)*FEAT + y)*WDIM + x4];
  #pragma unroll
  for (int c = 0; c < 12; c++) {
    float w0 = ew[c*3], w1 = ew[c*3+1], w2 = ew[c*3+2], bb = eb[c];
    float4 o;
    o.x = fmaf(xi0.x, w0, fmaf(xi1.x, w1, fmaf(xi2.x, w2, bb)));
    o.y = fmaf(xi0.y, w0, fmaf(xi1.y, w1, fmaf(xi2.y, w2, bb)));
    o.z = fmaf(xi0.z, w0, fmaf(xi1.z, w1, fmaf(xi2.z, w2, bb)));
    o.w = fmaf(xi0.w, w0, fmaf(xi1.w, w1, fmaf(xi2.w, w2, bb)));
    *(float4*)&h0[(((size_t)b*12+c)*FEAT + y)*WDIM + x4] = o;
  }
}

// ---------------- layernorm over feature axis (h), per (b,c,w) ----------------
__global__ __launch_bounds__(256)
void k_ln(const float* __restrict__ in, const float* __restrict__ w,
          const float* __restrict__ bia, float* __restrict__ out)
{
  int bc = blockIdx.y; int c = bc % 12;
  int w0 = blockIdx.x * 64;
  int tx = threadIdx.x & 63, ty = threadIdx.x >> 6;   // 64 x 4
  const float* base = in + (size_t)bc*PL + w0;
  float s = 0.f, ss = 0.f;
  for (int h = ty; h < FEAT; h += 4) {
    float v = base[(size_t)h*WDIM + tx];
    s += v; ss = fmaf(v, v, ss);
  }
  __shared__ float S1[4][64], S2[4][64];
  S1[ty][tx] = s; S2[ty][tx] = ss;
  __syncthreads();
  if (ty == 0) {
    float t1 = S1[0][tx]+S1[1][tx]+S1[2][tx]+S1[3][tx];
    float t2 = S2[0][tx]+S2[1][tx]+S2[2][tx]+S2[3][tx];
    float mu = t1 * (1.0f/1024.0f);
    float var = t2 * (1.0f/1024.0f) - mu*mu;
    S1[0][tx] = mu; S2[0][tx] = rsqrtf(var + 1e-8f);
  }
  __syncthreads();
  float mu = S1[0][tx], ri = S2[0][tx];
  float* ob = out + (size_t)bc*PL + w0;
  for (int h = ty; h < FEAT; h += 4) {
    float v = base[(size_t)h*WDIM + tx];
    ob[(size_t)h*WDIM + tx] = (v - mu) * ri * w[c*FEAT + h] + bia[c*FEAT + h];
  }
}

// ---------------- 9x9 depthwise conv, pad 4, 3 weight sets at once ----------------
__global__ __launch_bounds__(256)
void k_dw3(const float* __restrict__ in, const float* __restrict__ wq,
           const float* __restrict__ wk, const float* __restrict__ wv,
           float* __restrict__ oq, float* __restrict__ ok, float* __restrict__ ov)
{
  __shared__ float tile[12][72];
  __shared__ float wsq[81], wsk[81], wsv[81];
  int bc = blockIdx.z; int c = bc % 12;
  int y0 = blockIdx.y * 4, w0 = blockIdx.x * 64;
  int tid = threadIdx.x;
  const float* base = in + (size_t)bc*PL;
  for (int idx = tid; idx < 12*72; idx += 256) {
    int hh = idx / 72, ww = idx % 72;
    int gh = y0 + hh - 4, gw = w0 + ww - 4;
    float v = 0.f;
    if (gh >= 0 && gh < 1024 && gw >= 0 && gw < 512) v = base[(size_t)gh*WDIM + gw];
    tile[hh][ww] = v;
  }
  if (tid < 81) { wsq[tid] = wq[c*81+tid]; wsk[tid] = wk[c*81+tid]; wsv[tid] = wv[c*81+tid]; }
  __syncthreads();
  int tx = tid & 63, ty = tid >> 6;
  float aq = 0.f, ak = 0.f, av = 0.f;
  #pragma unroll
  for (int dy = 0; dy < 9; dy++)
    #pragma unroll
    for (int dx = 0; dx < 9; dx++) {
      float v = tile[ty+dy][tx+dx];
      aq = fmaf(v, wsq[dy*9+dx], aq);
      ak = fmaf(v, wsk[dy*9+dx], ak);
      av = fmaf(v, wsv[dy*9+dx], av);
    }
  size_t o = (size_t)bc*PL + (size_t)(y0+ty)*WDIM + (w0+tx);
  oq[o] = aq; ok[o] = ak; ov[o] = av;
}

// ---------------- RoPE in-place on Q,K (layout (b,c,head,w,d), d contiguous) ----------------
__global__ __launch_bounds__(256)
void k_rope(float* __restrict__ Qb, float* __restrict__ Kb)
{
  int t = blockIdx.x * 256 + threadIdx.x;   // 96*512*128
  int i = t & 127;
  int w = (t >> 7) & 511;
  int z = t >> 16;
  float inv = expf(-(float)i * 0.07195578415606394f);  // 10000^(-i/128)
  float ang = (float)w * inv;
  float s, cc; sincosf(ang, &s, &cc);
  size_t off = ((size_t)z*512 + w)*256 + 2*i;
  float2 q = *(float2*)&Qb[off];
  float2 k = *(float2*)&Kb[off];
  *(float2*)&Qb[off] = make_float2(q.x*cc - q.y*s, q.y*cc + q.x*s);
  *(float2*)&Kb[off] = make_float2(k.x*cc - k.y*s, k.y*cc + k.x*s);
}

// ---------------- row softmax (rows of 512), one wave per row ----------------
__global__ __launch_bounds__(256)
void k_softmax(const float* __restrict__ qk, float* __restrict__ probs)
{
  int wave = threadIdx.x >> 6, lane = threadIdx.x & 63;
  size_t row = (size_t)blockIdx.x * 4 + wave;
  const float* r = qk + row * 512;
  float v[8];
  float m = -1e30f;
  #pragma unroll
  for (int j = 0; j < 8; j++) { v[j] = r[lane + 64*j]; m = fmaxf(m, v[j]); }
  #pragma unroll
  for (int o = 32; o; o >>= 1) m = fmaxf(m, __shfl_xor(m, o));
  float s = 0.f;
  #pragma unroll
  for (int j = 0; j < 8; j++) { v[j] = expf(v[j] - m); s += v[j]; }
  #pragma unroll
  for (int o = 32; o; o >>= 1) s += __shfl_xor(s, o);
  float inv = 1.0f / s;
  float* p = probs + row * 512;
  #pragma unroll
  for (int j = 0; j < 8; j++) p[lane + 64*j] = v[j] * inv;
}

// ---------------- generic fp32 tiled GEMM, 4 modes ----------------
// MODE 0 QKV-proj: per z=(bc,head): C[d,w] = pw[c,head*256+d,:] . dw[bc]   -> Q[z][w][d]
// MODE 1 QK:       per z: C[q,k] = (Q[z] . K[z]^T) / 32                    -> qk row-major
// MODE 2 PV:       per z: C[q,d] = P[z] . V[z]                             -> att[bc][head*256+d][q]
// MODE 3 OPROJ:    per z=bc: C[f,w] = o_pw[c] . att[bc]  + h0 (in place)   -> h1 row-major
template<int MODE>
__global__ __launch_bounds__(256)
void gemm_k(const float* __restrict__ Abase, const float* __restrict__ Bbase,
            float* __restrict__ Cbase)
{
  constexpr int KD  = (MODE==1) ? 256 : ((MODE==2) ? 512 : 1024);
  constexpr int LDA = (MODE==0 || MODE==3) ? 1024 : ((MODE==1) ? 256 : 512);
  constexpr int LDB = (MODE==0 || MODE==3) ? 512 : 256;
  constexpr bool BT = (MODE==1);                    // B stored N x K (read transposed)
  constexpr int SM  = (MODE==0 || MODE==2) ? 1 : 512;
  constexpr int SN  = (MODE==0) ? 256 : ((MODE==2) ? 512 : 1);
  constexpr bool RES = (MODE==3);
  constexpr float SCL = (MODE==1) ? 0.03125f : 1.0f;

  const int z = blockIdx.z;
  const float* A; const float* B; float* C;
  if constexpr (MODE==0) {
    int bc = z >> 2, head = z & 3, c = bc % 12;
    A = Abase + (size_t)c*1048576 + (size_t)head*256*1024;
    B = Bbase + (size_t)bc*524288;
    C = Cbase + (size_t)z*131072;
  } else if constexpr (MODE==1) {
    A = Abase + (size_t)z*131072;
    B = Bbase + (size_t)z*131072;
    C = Cbase + (size_t)z*262144;
  } else if constexpr (MODE==2) {
    int bc = z >> 2, head = z & 3;
    A = Abase + (size_t)z*262144;
    B = Bbase + (size_t)z*131072;
    C = Cbase + (size_t)bc*524288 + (size_t)head*256*512;
  } else {
    int c = z % 12;
    A = Abase + (size_t)c*1048576;
    B = Bbase + (size_t)z*524288;
    C = Cbase + (size_t)z*524288;
  }

  __shared__ float As[16][68];
  __shared__ float Bs[16][68];

  const int tid = threadIdx.x;
  const int tx = tid & 15, ty = tid >> 4;
  const int m0 = blockIdx.y * 64, n0 = blockIdx.x * 64;
  const int lr = tid >> 2;           // 0..63
  const int lk = (tid & 3) * 4;      // 0,4,8,12

  float acc[4][4] = {};

  for (int k0 = 0; k0 < KD; k0 += 16) {
    float4 avv = *(const float4*)&A[(size_t)(m0+lr)*LDA + k0 + lk];
    As[lk+0][lr] = avv.x; As[lk+1][lr] = avv.y; As[lk+2][lr] = avv.z; As[lk+3][lr] = avv.w;
    if constexpr (BT) {
      float4 bvv = *(const float4*)&B[(size_t)(n0+lr)*LDB + k0 + lk];
      Bs[lk+0][lr] = bvv.x; Bs[lk+1][lr] = bvv.y; Bs[lk+2][lr] = bvv.z; Bs[lk+3][lr] = bvv.w;
    } else {
      int bk = tid >> 4;
      int bn = (tid & 15) * 4;
      *(float4*)&Bs[bk][bn] = *(const float4*)&B[(size_t)(k0+bk)*LDB + n0 + bn];
    }
    __syncthreads();
    #pragma unroll
    for (int kk = 0; kk < 16; kk++) {
      float4 a4 = *(const float4*)&As[kk][ty*4];
      float4 b4 = *(const float4*)&Bs[kk][tx*4];
      float ar[4] = {a4.x, a4.y, a4.z, a4.w};
      float br[4] = {b4.x, b4.y, b4.z, b4.w};
      #pragma unroll
      for (int i = 0; i < 4; i++)
        #pragma unroll
        for (int j = 0; j < 4; j++)
          acc[i][j] = fmaf(ar[i], br[j], acc[i][j]);
    }
    __syncthreads();
  }

  if constexpr (SM == 1) {
    // column-major-ish write: vectorize along m
    #pragma unroll
    for (int j = 0; j < 4; j++) {
      int n = n0 + tx*4 + j;
      float4 st = make_float4(acc[0][j]*SCL, acc[1][j]*SCL, acc[2][j]*SCL, acc[3][j]*SCL);
      *(float4*)&C[(size_t)n*SN + m0 + ty*4] = st;
    }
  } else {
    #pragma unroll
    for (int i = 0; i < 4; i++) {
      int m = m0 + ty*4 + i;
      size_t off = (size_t)m*SM + n0 + tx*4;
      float4 st = make_float4(acc[i][0]*SCL, acc[i][1]*SCL, acc[i][2]*SCL, acc[i][3]*SCL);
      if constexpr (RES) {
        float4 r = *(const float4*)&C[off];
        st.x += r.x; st.y += r.y; st.z += r.z; st.w += r.w;
      }
      *(float4*)&C[off] = st;
    }
  }
}

// ---------------- FFN conv1: 3x3, 12->48, relu^2 ----------------
__global__ __launch_bounds__(256)
void k_conv1(const float* __restrict__ in, const float* __restrict__ wgt,
             const float* __restrict__ bias, float* __restrict__ out)
{
  __shared__ float tile[12][6][66];
  int b = blockIdx.z;
  int y0 = blockIdx.y * 4, w0 = blockIdx.x * 64;
  int tid = threadIdx.x;
  for (int idx = tid; idx < 12*6*66; idx += 256) {
    int ic = idx / 396; int r = idx % 396; int hh = r / 66, ww = r % 66;
    int gh = y0 + hh - 1, gw = w0 + ww - 1;
    float v = 0.f;
    if (gh >= 0 && gh < 1024 && gw >= 0 && gw < 512)
      v = in[((size_t)(b*12+ic)*FEAT + gh)*WDIM + gw];
    tile[ic][hh][ww] = v;
  }
  __syncthreads();
  int tx = tid & 63, ty = tid >> 6;
  float acc[48];
  #pragma unroll
  for (int oc = 0; oc < 48; oc++) acc[oc] = bias[oc];
  for (int ic = 0; ic < 12; ic++) {
    #pragma unroll
    for (int dy = 0; dy < 3; dy++)
      #pragma unroll
      for (int dx = 0; dx < 3; dx++) {
        float v = tile[ic][ty+dy][tx+dx];
        const float* wp = wgt + ic*9 + dy*3 + dx;
        #pragma unroll
        for (int oc = 0; oc < 48; oc++) acc[oc] = fmaf(v, wp[oc*108], acc[oc]);
      }
  }
  int y = y0 + ty, xx = w0 + tx;
  #pragma unroll
  for (int oc = 0; oc < 48; oc++) {
    float r = fmaxf(acc[oc], 0.f);
    out[((size_t)(b*48+oc)*FEAT + y)*WDIM + xx] = r * r;
  }
}

// ---------------- FFN conv2: 3x3, 48->12, + residual, writes both outputs ----------------
__global__ __launch_bounds__(256)
void k_conv2(const float* __restrict__ in, const float* __restrict__ wgt,
             const float* __restrict__ bias, const float* __restrict__ h1,
             float* __restrict__ out0, float* __restrict__ out1)
{
  __shared__ float tile[12][6][66];
  int b = blockIdx.z;
  int y0 = blockIdx.y * 4, w0 = blockIdx.x * 64;
  int tid = threadIdx.x;
  int tx = tid & 63, ty = tid >> 6;
  float acc[12];
  #pragma unroll
  for (int oc = 0; oc < 12; oc++) acc[oc] = bias[oc];
  for (int g = 0; g < 4; g++) {
    __syncthreads();
    for (int idx = tid; idx < 12*6*66; idx += 256) {
      int ic = idx / 396; int r = idx % 396; int hh = r / 66, ww = r % 66;
      int gh = y0 + hh - 1, gw = w0 + ww - 1;
      float v = 0.f;
      if (gh >= 0 && gh < 1024 && gw >= 0 && gw < 512)
        v = in[((size_t)(b*48 + g*12 + ic)*FEAT + gh)*WDIM + gw];
      tile[ic][hh][ww] = v;
    }
    __syncthreads();
    for (int ic = 0; ic < 12; ic++) {
      #pragma unroll
      for (int dy = 0; dy < 3; dy++)
        #pragma unroll
        for (int dx = 0; dx < 3; dx++) {
          float v = tile[ic][ty+dy][tx+dx];
          const float* wp = wgt + (g*12+ic)*9 + dy*3 + dx;
          #pragma unroll
          for (int oc = 0; oc < 12; oc++) acc[oc] = fmaf(v, wp[oc*432], acc[oc]);
        }
    }
  }
  int y = y0 + ty, xx = w0 + tx;
  #pragma unroll
  for (int oc = 0; oc < 12; oc++) {
    size_t po = ((size_t)(b*12+oc)*FEAT + y)*WDIM + xx;
    float hv = acc[oc] + h1[po];
    out1[po] = hv;
    out0[((size_t)(b*15 + 3 + oc)*FEAT + y)*WDIM + xx] = hv;
  }
}

// ---------------- copy x into out0 channels 0..2 ----------------
__global__ __launch_bounds__(256)
void k_copyx(const float* __restrict__ x, float* __restrict__ out0)
{
  int t = blockIdx.x * 256 + threadIdx.x;   // 2*3*1024*128
  int x4 = (t & 127) * 4;
  int y  = (t >> 7) & 1023;
  int ci = (t >> 17) % 3;
  int b  = t / 393216;
  *(float4*)&out0[(((size_t)b*15 + ci)*FEAT + y)*WDIM + x4] =
      *(const float4*)&x[(((size_t)b*3 + ci)*FEAT + y)*WDIM + x4];
}

extern "C" void kernel_launch(void* const* d_in, const int* in_sizes, int n_in,
                              void* d_out, int out_size, void* d_ws, size_t ws_size,
                              hipStream_t stream)
{
  const float* x       = (const float*)d_in[0];
  const float* embed_w = (const float*)d_in[1];
  const float* embed_b = (const float*)d_in[2];
  const float* ln1_w   = (const float*)d_in[3];
  const float* ln1_b   = (const float*)d_in[4];
  const float* q_dw    = (const float*)d_in[5];
  const float* q_pw    = (const float*)d_in[6];
  const float* k_dw    = (const float*)d_in[7];
  const float* k_pw    = (const float*)d_in[8];
  const float* v_dw    = (const float*)d_in[9];
  const float* v_pw    = (const float*)d_in[10];
  const float* o_pw    = (const float*)d_in[11];
  const float* ln2_w   = (const float*)d_in[12];
  const float* ln2_b   = (const float*)d_in[13];
  const float* c1_w    = (const float*)d_in[14];
  const float* c1_b    = (const float*)d_in[15];
  const float* c2_w    = (const float*)d_in[16];
  const float* c2_b    = (const float*)d_in[17];

  // Compact 7-slot workspace (7*NB floats = 352 MB):
  //   slot0 h0 (h, then h+z in place)      lifetime: whole pipeline
  //   slot1 lnb (ln1 out, later ln2 out)
  //   slot2 dwq -> Vb -> tbuf[0]
  //   slot3 dwk -> probs[0] -> tbuf[1]
  //   slot4 dwv -> probs[1] -> tbuf[2]
  //   slot5 Qb  -> att      -> tbuf[3]
  //   slot6 Kb
  float* ws   = (float*)d_ws;
  float* h0   = ws + 0*NB;
  float* lnb  = ws + 1*NB;
  float* dwq  = ws + 2*NB;
  float* dwk  = ws + 3*NB;
  float* dwv  = ws + 4*NB;
  float* Qb   = ws + 5*NB;
  float* Kb   = ws + 6*NB;
  float* Vb   = ws + 2*NB;      // overlays dwq (dead after Q-proj)
  float* probs = ws + 3*NB;     // 2 slots; overlays dwk,dwv (dead after V-proj)
  float* att  = ws + 5*NB;      // overlays Qb (dead after QK^T)
  float* tbuf  = ws + 2*NB;     // 4 slots; overlays Vb/probs/att (dead after o-proj)

  float* out0 = (float*)d_out;                       // (2,15,1024,512)
  float* out1 = out0 + (size_t)2*15*FEAT*WDIM;       // (2,12,1024,512)
  float* qk   = out1 + NB;                           // (2,12,4,512,512)

  // 1. embed
  k_embed<<<1024, 256, 0, stream>>>(x, embed_w, embed_b, h0);
  // 2. LN1
  k_ln<<<dim3(8, 24), 256, 0, stream>>>(h0, ln1_w, ln1_b, lnb);
  // 3. depthwise 9x9 (q,k,v)
  k_dw3<<<dim3(8, 256, 24), 256, 0, stream>>>(lnb, q_dw, k_dw, v_dw, dwq, dwk, dwv);
  // 4. projections (order matters for buffer overlays: Q first, then K, then V)
  gemm_k<0><<<dim3(8, 4, 96), 256, 0, stream>>>(q_pw, dwq, Qb);
  gemm_k<0><<<dim3(8, 4, 96), 256, 0, stream>>>(k_pw, dwk, Kb);
  gemm_k<0><<<dim3(8, 4, 96), 256, 0, stream>>>(v_pw, dwv, Vb);
  // 5. RoPE on Q,K
  k_rope<<<24576, 256, 0, stream>>>(Qb, Kb);
  // 6. QK^T / 32  -> qk output
  gemm_k<1><<<dim3(8, 8, 96), 256, 0, stream>>>(Qb, Kb, qk);
  // 7. softmax
  k_softmax<<<12288, 256, 0, stream>>>(qk, probs);
  // 8. P.V -> att (b,c,f,w layout)
  gemm_k<2><<<dim3(4, 8, 96), 256, 0, stream>>>(probs, Vb, att);
  // 9. o-proj + residual (in place into h0 -> h1)
  gemm_k<3><<<dim3(8, 16, 24), 256, 0, stream>>>(o_pw, att, h0);
  // 10. LN2
  k_ln<<<dim3(8, 24), 256, 0, stream>>>(h0, ln2_w, ln2_b, lnb);
  // 11. conv1 + relu^2
  k_conv1<<<dim3(8, 256, 2), 256, 0, stream>>>(lnb, c1_w, c1_b, tbuf);
  // 12. conv2 + residual -> out1 and out0[3..14]
  k_conv2<<<dim3(8, 256, 2), 256, 0, stream>>>(tbuf, c2_w, c2_b, h0, out0, out1);
  // 13. x -> out0[0..2]
  k_copyx<<<3072, 256, 0, stream>>>(x, out0);
}

// Round 3
// 1786.136 us; speedup vs baseline: 1.7731x; 1.7731x over previous
//
#include <hip/hip_runtime.h>
#include <math.h>

static constexpr int FEAT = 1024;
static constexpr int WDIM = 512;
static constexpr size_t PL = (size_t)FEAT * WDIM;      // 524288 per (b,c) plane
static constexpr size_t NB = (size_t)2 * 12 * PL;      // 12582912 full tensor
static constexpr size_t HS = NB / 2;                   // floats per half-slot

typedef __attribute__((ext_vector_type(8))) short bf8_t;   // 8 bf16 (4 VGPR)
typedef __attribute__((ext_vector_type(4))) float f4_t;

__device__ __forceinline__ ushort f2b(float f) {
  union { float f; unsigned u; } x; x.f = f;
  unsigned u = x.u;
  return (ushort)((u + 0x7FFFu + ((u >> 16) & 1u)) >> 16);   // RNE
}

#define GLL16(g, l) __builtin_amdgcn_global_load_lds(                         \
    (const __attribute__((address_space(1))) void*)(g),                       \
    (__attribute__((address_space(3))) void*)(l), 16, 0, 0)

// ---------------- embed: 1x1 conv 3->12 ----------------
__global__ __launch_bounds__(256)
void k_embed(const float* __restrict__ x, const float* __restrict__ ew,
             const float* __restrict__ eb, float* __restrict__ h0)
{
  int t = blockIdx.x * 256 + threadIdx.x;      // 2*1024*128
  int x4 = (t & 127) * 4;
  int y  = (t >> 7) & 1023;
  int b  = t >> 17;
  float4 xi0 = *(const float4*)&x[(((size_t)b*3+0)*FEAT + y)*WDIM + x4];
  float4 xi1 = *(const float4*)&x[(((size_t)b*3+1)*FEAT + y)*WDIM + x4];
  float4 xi2 = *(const float4*)&x[(((size_t)b*3+2)*FEAT + y)*WDIM + x4];
  #pragma unroll
  for (int c = 0; c < 12; c++) {
    float w0 = ew[c*3], w1 = ew[c*3+1], w2 = ew[c*3+2], bb = eb[c];
    float4 o;
    o.x = fmaf(xi0.x, w0, fmaf(xi1.x, w1, fmaf(xi2.x, w2, bb)));
    o.y = fmaf(xi0.y, w0, fmaf(xi1.y, w1, fmaf(xi2.y, w2, bb)));
    o.z = fmaf(xi0.z, w0, fmaf(xi1.z, w1, fmaf(xi2.z, w2, bb)));
    o.w = fmaf(xi0.w, w0, fmaf(xi1.w, w1, fmaf(xi2.w, w2, bb)));
    *(float4*)&h0[(((size_t)b*12+c)*FEAT + y)*WDIM + x4] = o;
  }
}

// ---------------- layernorm over feature axis (h), per (b,c,w) ----------------
__global__ __launch_bounds__(256)
void k_ln(const float* __restrict__ in, const float* __restrict__ w,
          const float* __restrict__ bia, float* __restrict__ out)
{
  int bc = blockIdx.y; int c = bc % 12;
  int w0 = blockIdx.x * 64;
  int tx = threadIdx.x & 63, ty = threadIdx.x >> 6;   // 64 x 4
  const float* base = in + (size_t)bc*PL + w0;
  float s = 0.f, ss = 0.f;
  for (int h = ty; h < FEAT; h += 4) {
    float v = base[(size_t)h*WDIM + tx];
    s += v; ss = fmaf(v, v, ss);
  }
  __shared__ float S1[4][64], S2[4][64];
  S1[ty][tx] = s; S2[ty][tx] = ss;
  __syncthreads();
  if (ty == 0) {
    float t1 = S1[0][tx]+S1[1][tx]+S1[2][tx]+S1[3][tx];
    float t2 = S2[0][tx]+S2[1][tx]+S2[2][tx]+S2[3][tx];
    float mu = t1 * (1.0f/1024.0f);
    float var = t2 * (1.0f/1024.0f) - mu*mu;
    S1[0][tx] = mu; S2[0][tx] = rsqrtf(var + 1e-8f);
  }
  __syncthreads();
  float mu = S1[0][tx], ri = S2[0][tx];
  float* ob = out + (size_t)bc*PL + w0;
  for (int h = ty; h < FEAT; h += 4) {
    float v = base[(size_t)h*WDIM + tx];
    ob[(size_t)h*WDIM + tx] = (v - mu) * ri * w[c*FEAT + h] + bia[c*FEAT + h];
  }
}

// ---------------- 9x9 depthwise conv, pad 4, 3 weight sets at once ----------------
__global__ __launch_bounds__(256)
void k_dw3(const float* __restrict__ in, const float* __restrict__ wq,
           const float* __restrict__ wk, const float* __restrict__ wv,
           float* __restrict__ oq, float* __restrict__ ok, float* __restrict__ ov)
{
  __shared__ float tile[12][72];
  __shared__ float wsq[81], wsk[81], wsv[81];
  int bc = blockIdx.z; int c = bc % 12;
  int y0 = blockIdx.y * 4, w0 = blockIdx.x * 64;
  int tid = threadIdx.x;
  const float* base = in + (size_t)bc*PL;
  for (int idx = tid; idx < 12*72; idx += 256) {
    int hh = idx / 72, ww = idx % 72;
    int gh = y0 + hh - 4, gw = w0 + ww - 4;
    float v = 0.f;
    if (gh >= 0 && gh < 1024 && gw >= 0 && gw < 512) v = base[(size_t)gh*WDIM + gw];
    tile[hh][ww] = v;
  }
  if (tid < 81) { wsq[tid] = wq[c*81+tid]; wsk[tid] = wk[c*81+tid]; wsv[tid] = wv[c*81+tid]; }
  __syncthreads();
  int tx = tid & 63, ty = tid >> 6;
  float aq = 0.f, ak = 0.f, av = 0.f;
  #pragma unroll
  for (int dy = 0; dy < 9; dy++)
    #pragma unroll
    for (int dx = 0; dx < 9; dx++) {
      float v = tile[ty+dy][tx+dx];
      aq = fmaf(v, wsq[dy*9+dx], aq);
      ak = fmaf(v, wsk[dy*9+dx], ak);
      av = fmaf(v, wsv[dy*9+dx], av);
    }
  size_t o = (size_t)bc*PL + (size_t)(y0+ty)*WDIM + (w0+tx);
  oq[o] = aq; ok[o] = ak; ov[o] = av;
}

// ---------------- transpose+cvt: fp32 [h=1024][w=512] -> bf16 [w=512][h=1024], x3 ----------------
__global__ __launch_bounds__(256)
void k_tr3(const float* __restrict__ iq, const float* __restrict__ ik,
           const float* __restrict__ iv, ushort* __restrict__ oq,
           ushort* __restrict__ ok, ushort* __restrict__ ov)
{
  __shared__ float t[64][65];
  int bc = blockIdx.z; int h0 = blockIdx.y * 64, w0 = blockIdx.x * 64;
  size_t ib = (size_t)bc * PL;
  const float* ins[3] = {iq + ib, ik + ib, iv + ib};
  ushort* outs[3] = {oq + ib, ok + ib, ov + ib};
  #pragma unroll
  for (int a = 0; a < 3; a++) {
    if (a) __syncthreads();
    for (int i = threadIdx.x; i < 4096; i += 256) {
      int hh = i >> 6, ww = i & 63;
      t[hh][ww] = ins[a][(size_t)(h0+hh)*512 + w0 + ww];
    }
    __syncthreads();
    for (int i = threadIdx.x; i < 4096; i += 256) {
      int ww = i >> 6, hh = i & 63;
      outs[a][(size_t)(w0+ww)*1024 + h0 + hh] = f2b(t[hh][ww]);
    }
  }
}

// ---------------- fp32 -> bf16 flat convert (n = 12582912, 8 per thread) ----------------
__global__ __launch_bounds__(256)
void k_cvt(const float* __restrict__ in, ushort* __restrict__ out)
{
  size_t i = ((size_t)blockIdx.x * 256 + threadIdx.x) * 8;
  float4 v0 = *(const float4*)&in[i];
  float4 v1 = *(const float4*)&in[i+4];
  union { ushort u[8]; uint4 v; } o;
  o.u[0]=f2b(v0.x); o.u[1]=f2b(v0.y); o.u[2]=f2b(v0.z); o.u[3]=f2b(v0.w);
  o.u[4]=f2b(v1.x); o.u[5]=f2b(v1.y); o.u[6]=f2b(v1.z); o.u[7]=f2b(v1.w);
  *(uint4*)&out[i] = o.v;
}

// ---------------- row softmax (rows of 512), one wave per row, bf16 out ----------------
__global__ __launch_bounds__(256)
void k_softmax(const float* __restrict__ qk, ushort* __restrict__ probs)
{
  int wave = threadIdx.x >> 6, lane = threadIdx.x & 63;
  size_t row = (size_t)blockIdx.x * 4 + wave;
  const float* r = qk + row * 512;
  float v[8];
  float m = -1e30f;
  #pragma unroll
  for (int j = 0; j < 8; j++) { v[j] = r[lane + 64*j]; m = fmaxf(m, v[j]); }
  #pragma unroll
  for (int o = 32; o; o >>= 1) m = fmaxf(m, __shfl_xor(m, o));
  float s = 0.f;
  #pragma unroll
  for (int j = 0; j < 8; j++) { v[j] = expf(v[j] - m); s += v[j]; }
  #pragma unroll
  for (int o = 32; o; o >>= 1) s += __shfl_xor(s, o);
  float inv = 1.0f / s;
  ushort* p = probs + row * 512;
  #pragma unroll
  for (int j = 0; j < 8; j++) p[lane + 64*j] = f2b(v[j] * inv);
}

// ---------------- MFMA bf16 GEMM, fragment-ordered LDS, 128x128 tile ----------------
// All modes: C[M][N] = A[M][K] . B[N][K]^T (both K-contiguous bf16).
// MODE 0: proj Q/K. z=(bc,head). A=pw_bf16[c]+head*256 rows, B=dwt[bc] ([w][h]).
//         C -> Qb[z][w][d] bf16 WITH fused RoPE.
// MODE 4: proj V. Same A/B; C -> Vb[z][d][w] bf16 (no rope).
// MODE 1: QK^T/32. A=Qb[z] ([q][d]), B=Kb[z] ([k][d]). C -> qk fp32 row-major.
// MODE 2: PV. A=probs[z] ([q][k]), B=Vb[z] ([d][w=k]). C -> attt[bc][q][head*256+d] bf16.
// MODE 3: OPROJ. A=opw_bf16[c], B=attt[bc] ([w'][h]). C -> h0 += (fp32, in place).
template<int MODE>
__global__ __launch_bounds__(256)
void mgemm(const ushort* __restrict__ Ab, const ushort* __restrict__ Bb,
           void* __restrict__ Cb)
{
  constexpr int K   = (MODE==1) ? 256 : ((MODE==2) ? 512 : 1024);
  constexpr int LDA = (MODE==1) ? 256 : ((MODE==2) ? 512 : 1024);
  constexpr int LDB = LDA;

  const int z = blockIdx.z;
  const ushort* A; const ushort* B;
  if constexpr (MODE==0 || MODE==4) {
    int bc = z >> 2, head = z & 3, c = bc % 12;
    A = Ab + ((size_t)c*1024 + head*256)*1024;
    B = Bb + (size_t)bc*524288;
  } else if constexpr (MODE==1) {
    A = Ab + (size_t)z*131072; B = Bb + (size_t)z*131072;
  } else if constexpr (MODE==2) {
    A = Ab + (size_t)z*262144; B = Bb + (size_t)z*131072;
  } else {
    int c = z % 12;
    A = Ab + (size_t)c*1048576;
    B = Bb + (size_t)z*524288;
  }

  const int m0 = blockIdx.y * 128, n0 = blockIdx.x * 128;
  const int tid = threadIdx.x, lane = tid & 63, wv = tid >> 6;
  const int wr = wv >> 1, wc = wv & 1;
  const int lm = lane & 15, lg = lane >> 4;

  __shared__ __align__(16) ushort Alds[4096];   // 8 fragment slots x 512 bf16
  __shared__ __align__(16) ushort Blds[4096];

  // wave wv stages A slots {2wv,2wv+1} and B slots {2wv,2wv+1}
  const ushort* gA0 = A + (size_t)(m0 + (2*wv)*16 + lm)*LDA + 8*lg;
  const ushort* gA1 = gA0 + (size_t)16*LDA;
  const ushort* gB0 = B + (size_t)(n0 + (2*wv)*16 + lm)*LDB + 8*lg;
  const ushort* gB1 = gB0 + (size_t)16*LDB;
  ushort* lA0 = &Alds[(2*wv)*512]; ushort* lA1 = lA0 + 512;
  ushort* lB0 = &Blds[(2*wv)*512]; ushort* lB1 = lB0 + 512;

  f4_t acc[4][4];
  #pragma unroll
  for (int i = 0; i < 4; i++)
    #pragma unroll
    for (int j = 0; j < 4; j++) acc[i][j] = (f4_t){0.f, 0.f, 0.f, 0.f};

  for (int k0 = 0; k0 < K; k0 += 32) {
    GLL16(gA0 + k0, lA0); GLL16(gA1 + k0, lA1);
    GLL16(gB0 + k0, lB0); GLL16(gB1 + k0, lB1);
    __syncthreads();
    bf8_t fa[4], fb[4];
    #pragma unroll
    for (int i = 0; i < 4; i++) fa[i] = *(const bf8_t*)&Alds[(wr*4+i)*512 + lane*8];
    #pragma unroll
    for (int j = 0; j < 4; j++) fb[j] = *(const bf8_t*)&Blds[(wc*4+j)*512 + lane*8];
    #pragma unroll
    for (int i = 0; i < 4; i++)
      #pragma unroll
      for (int j = 0; j < 4; j++)
        acc[i][j] = __builtin_amdgcn_mfma_f32_16x16x32_bf16(fa[i], fb[j], acc[i][j], 0, 0, 0);
    __syncthreads();
  }

  // D fragment: col = lane&15, row = (lane>>4)*4 + reg  [m89-verified]
  if constexpr (MODE==0) {          // Qb[z][w][d] + RoPE
    ushort* C = (ushort*)Cb + (size_t)z*131072;
    #pragma unroll
    for (int j = 0; j < 4; j++) {
      int w = n0 + wc*64 + j*16 + lm;
      #pragma unroll
      for (int i = 0; i < 4; i++) {
        int d0 = m0 + wr*64 + i*16 + lg*4;
        int p0 = d0 >> 1;
        float inv0 = expf(-(float)p0 * 0.07195578432833848f);
        float inv1 = inv0 * 0.9305720409297794f;     // * exp(-ln(1e4)/128)
        float s0, c0, s1, c1;
        sincosf((float)w * inv0, &s0, &c0);
        sincosf((float)w * inv1, &s1, &c1);
        f4_t a = acc[i][j];
        ushort4 o;
        o.x = f2b(a.x*c0 - a.y*s0);
        o.y = f2b(a.y*c0 + a.x*s0);
        o.z = f2b(a.z*c1 - a.w*s1);
        o.w = f2b(a.w*c1 + a.z*s1);
        *(ushort4*)&C[(size_t)w*256 + d0] = o;
      }
    }
  } else if constexpr (MODE==4) {   // Vb[z][d][w]
    ushort* C = (ushort*)Cb + (size_t)z*131072;
    #pragma unroll
    for (int i = 0; i < 4; i++) {
      int d0 = m0 + wr*64 + i*16 + lg*4;
      #pragma unroll
      for (int j = 0; j < 4; j++) {
        int w = n0 + wc*64 + j*16 + lm;
        f4_t a = acc[i][j];
        C[(size_t)(d0+0)*512 + w] = f2b(a.x);
        C[(size_t)(d0+1)*512 + w] = f2b(a.y);
        C[(size_t)(d0+2)*512 + w] = f2b(a.z);
        C[(size_t)(d0+3)*512 + w] = f2b(a.w);
      }
    }
  } else if constexpr (MODE==1) {   // qk fp32, *1/32
    float* C = (float*)Cb + (size_t)z*262144;
    #pragma unroll
    for (int i = 0; i < 4; i++) {
      int q0 = m0 + wr*64 + i*16 + lg*4;
      #pragma unroll
      for (int j = 0; j < 4; j++) {
        int kc = n0 + wc*64 + j*16 + lm;
        f4_t a = acc[i][j];
        C[(size_t)(q0+0)*512 + kc] = a.x * 0.03125f;
        C[(size_t)(q0+1)*512 + kc] = a.y * 0.03125f;
        C[(size_t)(q0+2)*512 + kc] = a.z * 0.03125f;
        C[(size_t)(q0+3)*512 + kc] = a.w * 0.03125f;
      }
    }
  } else if constexpr (MODE==2) {   // attt[bc][q][head*256+d]
    ushort* C = (ushort*)Cb + (size_t)(z>>2)*524288 + (size_t)(z&3)*256;
    #pragma unroll
    for (int i = 0; i < 4; i++) {
      int q0 = m0 + wr*64 + i*16 + lg*4;
      #pragma unroll
      for (int j = 0; j < 4; j++) {
        int d = n0 + wc*64 + j*16 + lm;
        f4_t a = acc[i][j];
        C[(size_t)(q0+0)*1024 + d] = f2b(a.x);
        C[(size_t)(q0+1)*1024 + d] = f2b(a.y);
        C[(size_t)(q0+2)*1024 + d] = f2b(a.z);
        C[(size_t)(q0+3)*1024 + d] = f2b(a.w);
      }
    }
  } else {                          // MODE3: h0 += , fp32 in place
    float* C = (float*)Cb + (size_t)z*524288;
    #pragma unroll
    for (int i = 0; i < 4; i++) {
      int f0 = m0 + wr*64 + i*16 + lg*4;
      #pragma unroll
      for (int j = 0; j < 4; j++) {
        int w = n0 + wc*64 + j*16 + lm;
        f4_t a = acc[i][j];
        C[(size_t)(f0+0)*512 + w] += a.x;
        C[(size_t)(f0+1)*512 + w] += a.y;
        C[(size_t)(f0+2)*512 + w] += a.z;
        C[(size_t)(f0+3)*512 + w] += a.w;
      }
    }
  }
}

// ---------------- FFN conv1: 3x3, 12->48, relu^2 ----------------
__global__ __launch_bounds__(256)
void k_conv1(const float* __restrict__ in, const float* __restrict__ wgt,
             const float* __restrict__ bias, float* __restrict__ out)
{
  __shared__ float tile[12][6][66];
  int b = blockIdx.z;
  int y0 = blockIdx.y * 4, w0 = blockIdx.x * 64;
  int tid = threadIdx.x;
  for (int idx = tid; idx < 12*6*66; idx += 256) {
    int ic = idx / 396; int r = idx % 396; int hh = r / 66, ww = r % 66;
    int gh = y0 + hh - 1, gw = w0 + ww - 1;
    float v = 0.f;
    if (gh >= 0 && gh < 1024 && gw >= 0 && gw < 512)
      v = in[((size_t)(b*12+ic)*FEAT + gh)*WDIM + gw];
    tile[ic][hh][ww] = v;
  }
  __syncthreads();
  int tx = tid & 63, ty = tid >> 6;
  float acc[48];
  #pragma unroll
  for (int oc = 0; oc < 48; oc++) acc[oc] = bias[oc];
  for (int ic = 0; ic < 12; ic++) {
    #pragma unroll
    for (int dy = 0; dy < 3; dy++)
      #pragma unroll
      for (int dx = 0; dx < 3; dx++) {
        float v = tile[ic][ty+dy][tx+dx];
        const float* wp = wgt + ic*9 + dy*3 + dx;
        #pragma unroll
        for (int oc = 0; oc < 48; oc++) acc[oc] = fmaf(v, wp[oc*108], acc[oc]);
      }
  }
  int y = y0 + ty, xx = w0 + tx;
  #pragma unroll
  for (int oc = 0; oc < 48; oc++) {
    float r = fmaxf(acc[oc], 0.f);
    out[((size_t)(b*48+oc)*FEAT + y)*WDIM + xx] = r * r;
  }
}

// ---------------- FFN conv2: 3x3, 48->12, + residual, writes both outputs ----------------
__global__ __launch_bounds__(256)
void k_conv2(const float* __restrict__ in, const float* __restrict__ wgt,
             const float* __restrict__ bias, const float* __restrict__ h1,
             float* __restrict__ out0, float* __restrict__ out1)
{
  __shared__ float tile[12][6][66];
  int b = blockIdx.z;
  int y0 = blockIdx.y * 4, w0 = blockIdx.x * 64;
  int tid = threadIdx.x;
  int tx = tid & 63, ty = tid >> 6;
  float acc[12];
  #pragma unroll
  for (int oc = 0; oc < 12; oc++) acc[oc] = bias[oc];
  for (int g = 0; g < 4; g++) {
    __syncthreads();
    for (int idx = tid; idx < 12*6*66; idx += 256) {
      int ic = idx / 396; int r = idx % 396; int hh = r / 66, ww = r % 66;
      int gh = y0 + hh - 1, gw = w0 + ww - 1;
      float v = 0.f;
      if (gh >= 0 && gh < 1024 && gw >= 0 && gw < 512)
        v = in[((size_t)(b*48 + g*12 + ic)*FEAT + gh)*WDIM + gw];
      tile[ic][hh][ww] = v;
    }
    __syncthreads();
    for (int ic = 0; ic < 12; ic++) {
      #pragma unroll
      for (int dy = 0; dy < 3; dy++)
        #pragma unroll
        for (int dx = 0; dx < 3; dx++) {
          float v = tile[ic][ty+dy][tx+dx];
          const float* wp = wgt + (g*12+ic)*9 + dy*3 + dx;
          #pragma unroll
          for (int oc = 0; oc < 12; oc++) acc[oc] = fmaf(v, wp[oc*432], acc[oc]);
        }
    }
  }
  int y = y0 + ty, xx = w0 + tx;
  #pragma unroll
  for (int oc = 0; oc < 12; oc++) {
    size_t po = ((size_t)(b*12+oc)*FEAT + y)*WDIM + xx;
    float hv = acc[oc] + h1[po];
    out1[po] = hv;
    out0[((size_t)(b*15 + 3 + oc)*FEAT + y)*WDIM + xx] = hv;
  }
}

// ---------------- copy x into out0 channels 0..2 ----------------
__global__ __launch_bounds__(256)
void k_copyx(const float* __restrict__ x, float* __restrict__ out0)
{
  int t = blockIdx.x * 256 + threadIdx.x;   // 2*3*1024*128
  int x4 = (t & 127) * 4;
  int y  = (t >> 7) & 1023;
  int ci = (t >> 17) % 3;
  int b  = t / 393216;
  *(float4*)&out0[(((size_t)b*15 + ci)*FEAT + y)*WDIM + x4] =
      *(const float4*)&x[(((size_t)b*3 + ci)*FEAT + y)*WDIM + x4];
}

extern "C" void kernel_launch(void* const* d_in, const int* in_sizes, int n_in,
                              void* d_out, int out_size, void* d_ws, size_t ws_size,
                              hipStream_t stream)
{
  const float* x       = (const float*)d_in[0];
  const float* embed_w = (const float*)d_in[1];
  const float* embed_b = (const float*)d_in[2];
  const float* ln1_w   = (const float*)d_in[3];
  const float* ln1_b   = (const float*)d_in[4];
  const float* q_dw    = (const float*)d_in[5];
  const float* q_pw    = (const float*)d_in[6];
  const float* k_dw    = (const float*)d_in[7];
  const float* k_pw    = (const float*)d_in[8];
  const float* v_dw    = (const float*)d_in[9];
  const float* v_pw    = (const float*)d_in[10];
  const float* o_pw    = (const float*)d_in[11];
  const float* ln2_w   = (const float*)d_in[12];
  const float* ln2_b   = (const float*)d_in[13];
  const float* c1_w    = (const float*)d_in[14];
  const float* c1_b    = (const float*)d_in[15];
  const float* c2_w    = (const float*)d_in[16];
  const float* c2_b    = (const float*)d_in[17];

  // 14 half-slots (HS = NB/2 floats each) = 7*NB floats = 352 MB total.
  //   H0,H1 h0 | H2,H3 lnb | H4,H5 dwq->pwbq,pwbk | H6,H7 dwk->pwbv,pwbo
  //   H8,H9 dwv->Qb,Kb | H10 dwtq->probs lo | H11 dwtk->probs hi
  //   H12 dwtv->attt | H13 Vb ; tbuf = H4..H11 (4*NB fp32)
  float* ws = (float*)d_ws;
  float*  h0   = ws + 0*HS;
  float*  lnb  = ws + 2*HS;
  float*  dwq  = ws + 4*HS;
  float*  dwk  = ws + 6*HS;
  float*  dwv  = ws + 8*HS;
  ushort* dwtq = (ushort*)(ws + 10*HS);
  ushort* dwtk = (ushort*)(ws + 11*HS);
  ushort* dwtv = (ushort*)(ws + 12*HS);
  ushort* pwbq = (ushort*)(ws + 4*HS);
  ushort* pwbk = (ushort*)(ws + 5*HS);
  ushort* pwbv = (ushort*)(ws + 6*HS);
  ushort* pwbo = (ushort*)(ws + 7*HS);
  ushort* Qb   = (ushort*)(ws + 8*HS);
  ushort* Kb   = (ushort*)(ws + 9*HS);
  ushort* Vb   = (ushort*)(ws + 13*HS);
  ushort* probs= (ushort*)(ws + 10*HS);
  ushort* attt = (ushort*)(ws + 12*HS);
  float*  tbuf = ws + 4*HS;

  float* out0 = (float*)d_out;                       // (2,15,1024,512)
  float* out1 = out0 + (size_t)2*15*FEAT*WDIM;       // (2,12,1024,512)
  float* qk   = out1 + NB;                           // (2,12,4,512,512)

  k_embed<<<1024, 256, 0, stream>>>(x, embed_w, embed_b, h0);
  k_ln<<<dim3(8, 24), 256, 0, stream>>>(h0, ln1_w, ln1_b, lnb);
  k_dw3<<<dim3(8, 256, 24), 256, 0, stream>>>(lnb, q_dw, k_dw, v_dw, dwq, dwk, dwv);
  k_tr3<<<dim3(8, 16, 24), 256, 0, stream>>>(dwq, dwk, dwv, dwtq, dwtk, dwtv);
  k_cvt<<<6144, 256, 0, stream>>>(q_pw, pwbq);
  k_cvt<<<6144, 256, 0, stream>>>(k_pw, pwbk);
  k_cvt<<<6144, 256, 0, stream>>>(v_pw, pwbv);
  k_cvt<<<6144, 256, 0, stream>>>(o_pw, pwbo);
  // projections (RoPE fused for Q,K)
  mgemm<0><<<dim3(4, 2, 96), 256, 0, stream>>>(pwbq, dwtq, Qb);
  mgemm<0><<<dim3(4, 2, 96), 256, 0, stream>>>(pwbk, dwtk, Kb);
  mgemm<4><<<dim3(4, 2, 96), 256, 0, stream>>>(pwbv, dwtv, Vb);
  // QK^T / 32 -> qk output (fp32)
  mgemm<1><<<dim3(4, 4, 96), 256, 0, stream>>>(Qb, Kb, qk);
  k_softmax<<<12288, 256, 0, stream>>>(qk, probs);
  // P.V -> attt[bc][q][h]
  mgemm<2><<<dim3(2, 4, 96), 256, 0, stream>>>(probs, Vb, attt);
  // o-proj + residual in place into h0
  mgemm<3><<<dim3(4, 8, 24), 256, 0, stream>>>(pwbo, attt, (void*)h0);
  k_ln<<<dim3(8, 24), 256, 0, stream>>>(h0, ln2_w, ln2_b, lnb);
  k_conv1<<<dim3(8, 256, 2), 256, 0, stream>>>(lnb, c1_w, c1_b, tbuf);
  k_conv2<<<dim3(8, 256, 2), 256, 0, stream>>>(tbuf, c2_w, c2_b, h0, out0, out1);
  k_copyx<<<3072, 256, 0, stream>>>(x, out0);
}

// Round 4
// 1337.228 us; speedup vs baseline: 2.3683x; 1.3357x over previous
//
#include <hip/hip_runtime.h>
#include <math.h>

static constexpr int FEAT = 1024;
static constexpr int WDIM = 512;
static constexpr size_t PL = (size_t)FEAT * WDIM;      // 524288 per (b,c) plane
static constexpr size_t NB = (size_t)2 * 12 * PL;      // 12582912 full tensor
static constexpr size_t HS = NB / 2;                   // floats per half-slot

typedef __attribute__((ext_vector_type(8))) short bf8_t;   // 8 bf16 (4 VGPR)
typedef __attribute__((ext_vector_type(4))) float f4_t;

__device__ __forceinline__ ushort f2b(float f) {
  union { float f; unsigned u; } x; x.f = f;
  unsigned u = x.u;
  return (ushort)((u + 0x7FFFu + ((u >> 16) & 1u)) >> 16);   // RNE
}

#define GLL16(g, l) __builtin_amdgcn_global_load_lds(                         \
    (const __attribute__((address_space(1))) void*)(g),                       \
    (__attribute__((address_space(3))) void*)(l), 16, 0, 0)

// ---------------- embed: 1x1 conv 3->12 ----------------
__global__ __launch_bounds__(256)
void k_embed(const float* __restrict__ x, const float* __restrict__ ew,
             const float* __restrict__ eb, float* __restrict__ h0)
{
  int t = blockIdx.x * 256 + threadIdx.x;      // 2*1024*128
  int x4 = (t & 127) * 4;
  int y  = (t >> 7) & 1023;
  int b  = t >> 17;
  float4 xi0 = *(const float4*)&x[(((size_t)b*3+0)*FEAT + y)*WDIM + x4];
  float4 xi1 = *(const float4*)&x[(((size_t)b*3+1)*FEAT + y)*WDIM + x4];
  float4 xi2 = *(const float4*)&x[(((size_t)b*3+2)*FEAT + y)*WDIM + x4];
  #pragma unroll
  for (int c = 0; c < 12; c++) {
    float w0 = ew[c*3], w1 = ew[c*3+1], w2 = ew[c*3+2], bb = eb[c];
    float4 o;
    o.x = fmaf(xi0.x, w0, fmaf(xi1.x, w1, fmaf(xi2.x, w2, bb)));
    o.y = fmaf(xi0.y, w0, fmaf(xi1.y, w1, fmaf(xi2.y, w2, bb)));
    o.z = fmaf(xi0.z, w0, fmaf(xi1.z, w1, fmaf(xi2.z, w2, bb)));
    o.w = fmaf(xi0.w, w0, fmaf(xi1.w, w1, fmaf(xi2.w, w2, bb)));
    *(float4*)&h0[(((size_t)b*12+c)*FEAT + y)*WDIM + x4] = o;
  }
}

// ---------------- layernorm over feature axis (h), per (b,c,w), fp32 out ----------------
__global__ __launch_bounds__(256)
void k_ln(const float* __restrict__ in, const float* __restrict__ w,
          const float* __restrict__ bia, float* __restrict__ out)
{
  int bc = blockIdx.y; int c = bc % 12;
  int w0 = blockIdx.x * 64;
  int tx = threadIdx.x & 63, ty = threadIdx.x >> 6;   // 64 x 4
  const float* base = in + (size_t)bc*PL + w0;
  float s = 0.f, ss = 0.f;
  for (int h = ty; h < FEAT; h += 4) {
    float v = base[(size_t)h*WDIM + tx];
    s += v; ss = fmaf(v, v, ss);
  }
  __shared__ float S1[4][64], S2[4][64];
  S1[ty][tx] = s; S2[ty][tx] = ss;
  __syncthreads();
  if (ty == 0) {
    float t1 = S1[0][tx]+S1[1][tx]+S1[2][tx]+S1[3][tx];
    float t2 = S2[0][tx]+S2[1][tx]+S2[2][tx]+S2[3][tx];
    float mu = t1 * (1.0f/1024.0f);
    float var = t2 * (1.0f/1024.0f) - mu*mu;
    S1[0][tx] = mu; S2[0][tx] = rsqrtf(var + 1e-8f);
  }
  __syncthreads();
  float mu = S1[0][tx], ri = S2[0][tx];
  float* ob = out + (size_t)bc*PL + w0;
  for (int h = ty; h < FEAT; h += 4) {
    float v = base[(size_t)h*WDIM + tx];
    ob[(size_t)h*WDIM + tx] = (v - mu) * ri * w[c*FEAT + h] + bia[c*FEAT + h];
  }
}

// ---------------- layernorm variant: bf16 planar out (feeds conv1) ----------------
__global__ __launch_bounds__(256)
void k_ln_b(const float* __restrict__ in, const float* __restrict__ w,
            const float* __restrict__ bia, ushort* __restrict__ out)
{
  int bc = blockIdx.y; int c = bc % 12;
  int w0 = blockIdx.x * 64;
  int tx = threadIdx.x & 63, ty = threadIdx.x >> 6;
  const float* base = in + (size_t)bc*PL + w0;
  float s = 0.f, ss = 0.f;
  for (int h = ty; h < FEAT; h += 4) {
    float v = base[(size_t)h*WDIM + tx];
    s += v; ss = fmaf(v, v, ss);
  }
  __shared__ float S1[4][64], S2[4][64];
  S1[ty][tx] = s; S2[ty][tx] = ss;
  __syncthreads();
  if (ty == 0) {
    float t1 = S1[0][tx]+S1[1][tx]+S1[2][tx]+S1[3][tx];
    float t2 = S2[0][tx]+S2[1][tx]+S2[2][tx]+S2[3][tx];
    float mu = t1 * (1.0f/1024.0f);
    float var = t2 * (1.0f/1024.0f) - mu*mu;
    S1[0][tx] = mu; S2[0][tx] = rsqrtf(var + 1e-8f);
  }
  __syncthreads();
  float mu = S1[0][tx], ri = S2[0][tx];
  ushort* ob = out + (size_t)bc*PL + w0;
  for (int h = ty; h < FEAT; h += 4) {
    float v = base[(size_t)h*WDIM + tx];
    ob[(size_t)h*WDIM + tx] = f2b((v - mu) * ri * w[c*FEAT + h] + bia[c*FEAT + h]);
  }
}

// ---------------- 9x9 depthwise conv, pad 4, 3 weight sets at once ----------------
__global__ __launch_bounds__(256)
void k_dw3(const float* __restrict__ in, const float* __restrict__ wq,
           const float* __restrict__ wk, const float* __restrict__ wv,
           float* __restrict__ oq, float* __restrict__ ok, float* __restrict__ ov)
{
  __shared__ float tile[12][72];
  __shared__ float wsq[81], wsk[81], wsv[81];
  int bc = blockIdx.z; int c = bc % 12;
  int y0 = blockIdx.y * 4, w0 = blockIdx.x * 64;
  int tid = threadIdx.x;
  const float* base = in + (size_t)bc*PL;
  for (int idx = tid; idx < 12*72; idx += 256) {
    int hh = idx / 72, ww = idx % 72;
    int gh = y0 + hh - 4, gw = w0 + ww - 4;
    float v = 0.f;
    if (gh >= 0 && gh < 1024 && gw >= 0 && gw < 512) v = base[(size_t)gh*WDIM + gw];
    tile[hh][ww] = v;
  }
  if (tid < 81) { wsq[tid] = wq[c*81+tid]; wsk[tid] = wk[c*81+tid]; wsv[tid] = wv[c*81+tid]; }
  __syncthreads();
  int tx = tid & 63, ty = tid >> 6;
  float aq = 0.f, ak = 0.f, av = 0.f;
  #pragma unroll
  for (int dy = 0; dy < 9; dy++)
    #pragma unroll
    for (int dx = 0; dx < 9; dx++) {
      float v = tile[ty+dy][tx+dx];
      aq = fmaf(v, wsq[dy*9+dx], aq);
      ak = fmaf(v, wsk[dy*9+dx], ak);
      av = fmaf(v, wsv[dy*9+dx], av);
    }
  size_t o = (size_t)bc*PL + (size_t)(y0+ty)*WDIM + (w0+tx);
  oq[o] = aq; ok[o] = ak; ov[o] = av;
}

// ---------------- transpose+cvt: fp32 [h=1024][w=512] -> bf16 [w=512][h=1024], x3 ----------------
__global__ __launch_bounds__(256)
void k_tr3(const float* __restrict__ iq, const float* __restrict__ ik,
           const float* __restrict__ iv, ushort* __restrict__ oq,
           ushort* __restrict__ ok, ushort* __restrict__ ov)
{
  __shared__ float t[64][65];
  int bc = blockIdx.z; int h0 = blockIdx.y * 64, w0 = blockIdx.x * 64;
  size_t ib = (size_t)bc * PL;
  const float* ins[3] = {iq + ib, ik + ib, iv + ib};
  ushort* outs[3] = {oq + ib, ok + ib, ov + ib};
  #pragma unroll
  for (int a = 0; a < 3; a++) {
    if (a) __syncthreads();
    for (int i = threadIdx.x; i < 4096; i += 256) {
      int hh = i >> 6, ww = i & 63;
      t[hh][ww] = ins[a][(size_t)(h0+hh)*512 + w0 + ww];
    }
    __syncthreads();
    for (int i = threadIdx.x; i < 4096; i += 256) {
      int ww = i >> 6, hh = i & 63;
      outs[a][(size_t)(w0+ww)*1024 + h0 + hh] = f2b(t[hh][ww]);
    }
  }
}

// ---------------- fp32 -> bf16 flat convert (n = 12582912, 8 per thread) ----------------
__global__ __launch_bounds__(256)
void k_cvt(const float* __restrict__ in, ushort* __restrict__ out)
{
  size_t i = ((size_t)blockIdx.x * 256 + threadIdx.x) * 8;
  float4 v0 = *(const float4*)&in[i];
  float4 v1 = *(const float4*)&in[i+4];
  union { ushort u[8]; uint4 v; } o;
  o.u[0]=f2b(v0.x); o.u[1]=f2b(v0.y); o.u[2]=f2b(v0.z); o.u[3]=f2b(v0.w);
  o.u[4]=f2b(v1.x); o.u[5]=f2b(v1.y); o.u[6]=f2b(v1.z); o.u[7]=f2b(v1.w);
  *(uint4*)&out[i] = o.v;
}

// ---------------- row softmax (rows of 512), one wave per row, bf16 out ----------------
__global__ __launch_bounds__(256)
void k_softmax(const float* __restrict__ qk, ushort* __restrict__ probs)
{
  int wave = threadIdx.x >> 6, lane = threadIdx.x & 63;
  size_t row = (size_t)blockIdx.x * 4 + wave;
  const float* r = qk + row * 512;
  float v[8];
  float m = -1e30f;
  #pragma unroll
  for (int j = 0; j < 8; j++) { v[j] = r[lane + 64*j]; m = fmaxf(m, v[j]); }
  #pragma unroll
  for (int o = 32; o; o >>= 1) m = fmaxf(m, __shfl_xor(m, o));
  float s = 0.f;
  #pragma unroll
  for (int j = 0; j < 8; j++) { v[j] = expf(v[j] - m); s += v[j]; }
  #pragma unroll
  for (int o = 32; o; o >>= 1) s += __shfl_xor(s, o);
  float inv = 1.0f / s;
  ushort* p = probs + row * 512;
  #pragma unroll
  for (int j = 0; j < 8; j++) p[lane + 64*j] = f2b(v[j] * inv);
}

// ---------------- MFMA bf16 GEMM, fragment-ordered LDS, 128x128 tile ----------------
template<int MODE>
__global__ __launch_bounds__(256)
void mgemm(const ushort* __restrict__ Ab, const ushort* __restrict__ Bb,
           void* __restrict__ Cb)
{
  constexpr int K   = (MODE==1) ? 256 : ((MODE==2) ? 512 : 1024);
  constexpr int LDA = (MODE==1) ? 256 : ((MODE==2) ? 512 : 1024);
  constexpr int LDB = LDA;

  const int z = blockIdx.z;
  const ushort* A; const ushort* B;
  if constexpr (MODE==0 || MODE==4) {
    int bc = z >> 2, head = z & 3, c = bc % 12;
    A = Ab + ((size_t)c*1024 + head*256)*1024;
    B = Bb + (size_t)bc*524288;
  } else if constexpr (MODE==1) {
    A = Ab + (size_t)z*131072; B = Bb + (size_t)z*131072;
  } else if constexpr (MODE==2) {
    A = Ab + (size_t)z*262144; B = Bb + (size_t)z*131072;
  } else {
    int c = z % 12;
    A = Ab + (size_t)c*1048576;
    B = Bb + (size_t)z*524288;
  }

  const int m0 = blockIdx.y * 128, n0 = blockIdx.x * 128;
  const int tid = threadIdx.x, lane = tid & 63, wv = tid >> 6;
  const int wr = wv >> 1, wc = wv & 1;
  const int lm = lane & 15, lg = lane >> 4;

  __shared__ __align__(16) ushort Alds[4096];
  __shared__ __align__(16) ushort Blds[4096];

  const ushort* gA0 = A + (size_t)(m0 + (2*wv)*16 + lm)*LDA + 8*lg;
  const ushort* gA1 = gA0 + (size_t)16*LDA;
  const ushort* gB0 = B + (size_t)(n0 + (2*wv)*16 + lm)*LDB + 8*lg;
  const ushort* gB1 = gB0 + (size_t)16*LDB;
  ushort* lA0 = &Alds[(2*wv)*512]; ushort* lA1 = lA0 + 512;
  ushort* lB0 = &Blds[(2*wv)*512]; ushort* lB1 = lB0 + 512;

  f4_t acc[4][4];
  #pragma unroll
  for (int i = 0; i < 4; i++)
    #pragma unroll
    for (int j = 0; j < 4; j++) acc[i][j] = (f4_t){0.f, 0.f, 0.f, 0.f};

  for (int k0 = 0; k0 < K; k0 += 32) {
    GLL16(gA0 + k0, lA0); GLL16(gA1 + k0, lA1);
    GLL16(gB0 + k0, lB0); GLL16(gB1 + k0, lB1);
    __syncthreads();
    bf8_t fa[4], fb[4];
    #pragma unroll
    for (int i = 0; i < 4; i++) fa[i] = *(const bf8_t*)&Alds[(wr*4+i)*512 + lane*8];
    #pragma unroll
    for (int j = 0; j < 4; j++) fb[j] = *(const bf8_t*)&Blds[(wc*4+j)*512 + lane*8];
    #pragma unroll
    for (int i = 0; i < 4; i++)
      #pragma unroll
      for (int j = 0; j < 4; j++)
        acc[i][j] = __builtin_amdgcn_mfma_f32_16x16x32_bf16(fa[i], fb[j], acc[i][j], 0, 0, 0);
    __syncthreads();
  }

  if constexpr (MODE==0) {          // Qb[z][w][d] + RoPE
    ushort* C = (ushort*)Cb + (size_t)z*131072;
    #pragma unroll
    for (int j = 0; j < 4; j++) {
      int w = n0 + wc*64 + j*16 + lm;
      #pragma unroll
      for (int i = 0; i < 4; i++) {
        int d0 = m0 + wr*64 + i*16 + lg*4;
        int p0 = d0 >> 1;
        float inv0 = expf(-(float)p0 * 0.07195578432833848f);
        float inv1 = inv0 * 0.9305720409297794f;
        float s0, c0, s1, c1;
        sincosf((float)w * inv0, &s0, &c0);
        sincosf((float)w * inv1, &s1, &c1);
        f4_t a = acc[i][j];
        ushort4 o;
        o.x = f2b(a.x*c0 - a.y*s0);
        o.y = f2b(a.y*c0 + a.x*s0);
        o.z = f2b(a.z*c1 - a.w*s1);
        o.w = f2b(a.w*c1 + a.z*s1);
        *(ushort4*)&C[(size_t)w*256 + d0] = o;
      }
    }
  } else if constexpr (MODE==4) {   // Vb[z][d][w]
    ushort* C = (ushort*)Cb + (size_t)z*131072;
    #pragma unroll
    for (int i = 0; i < 4; i++) {
      int d0 = m0 + wr*64 + i*16 + lg*4;
      #pragma unroll
      for (int j = 0; j < 4; j++) {
        int w = n0 + wc*64 + j*16 + lm;
        f4_t a = acc[i][j];
        C[(size_t)(d0+0)*512 + w] = f2b(a.x);
        C[(size_t)(d0+1)*512 + w] = f2b(a.y);
        C[(size_t)(d0+2)*512 + w] = f2b(a.z);
        C[(size_t)(d0+3)*512 + w] = f2b(a.w);
      }
    }
  } else if constexpr (MODE==1) {   // qk fp32, *1/32
    float* C = (float*)Cb + (size_t)z*262144;
    #pragma unroll
    for (int i = 0; i < 4; i++) {
      int q0 = m0 + wr*64 + i*16 + lg*4;
      #pragma unroll
      for (int j = 0; j < 4; j++) {
        int kc = n0 + wc*64 + j*16 + lm;
        f4_t a = acc[i][j];
        C[(size_t)(q0+0)*512 + kc] = a.x * 0.03125f;
        C[(size_t)(q0+1)*512 + kc] = a.y * 0.03125f;
        C[(size_t)(q0+2)*512 + kc] = a.z * 0.03125f;
        C[(size_t)(q0+3)*512 + kc] = a.w * 0.03125f;
      }
    }
  } else if constexpr (MODE==2) {   // attt[bc][q][head*256+d]
    ushort* C = (ushort*)Cb + (size_t)(z>>2)*524288 + (size_t)(z&3)*256;
    #pragma unroll
    for (int i = 0; i < 4; i++) {
      int q0 = m0 + wr*64 + i*16 + lg*4;
      #pragma unroll
      for (int j = 0; j < 4; j++) {
        int d = n0 + wc*64 + j*16 + lm;
        f4_t a = acc[i][j];
        C[(size_t)(q0+0)*1024 + d] = f2b(a.x);
        C[(size_t)(q0+1)*1024 + d] = f2b(a.y);
        C[(size_t)(q0+2)*1024 + d] = f2b(a.z);
        C[(size_t)(q0+3)*1024 + d] = f2b(a.w);
      }
    }
  } else {                          // MODE3: h0 += , fp32 in place
    float* C = (float*)Cb + (size_t)z*524288;
    #pragma unroll
    for (int i = 0; i < 4; i++) {
      int f0 = m0 + wr*64 + i*16 + lg*4;
      #pragma unroll
      for (int j = 0; j < 4; j++) {
        int w = n0 + wc*64 + j*16 + lm;
        f4_t a = acc[i][j];
        C[(size_t)(f0+0)*512 + w] += a.x;
        C[(size_t)(f0+1)*512 + w] += a.y;
        C[(size_t)(f0+2)*512 + w] += a.z;
        C[(size_t)(f0+3)*512 + w] += a.w;
      }
    }
  }
}

// ---------------- pack FFN conv weights to MFMA layouts (bf16, zero-padded) ----------------
// Wp1[oc=48][K=168pad]: k = ofs*16+ch, ofs=dy*3+dx (<9), ch<12 real
// Wp2[oc=16][K=584pad]: k = ofs*64+ch, ch<48 real, oc<12 real
__global__ __launch_bounds__(256)
void k_pack(const float* __restrict__ c1w, const float* __restrict__ c2w,
            ushort* __restrict__ wp1, ushort* __restrict__ wp2)
{
  int tid = threadIdx.x;
  for (int i = tid; i < 48*168; i += 256) {
    int oc = i / 168, k = i % 168;
    ushort v = 0;
    if (k < 160) {
      int ofs = k >> 4, ch = k & 15;
      if (ofs < 9 && ch < 12) v = f2b(c1w[(oc*12 + ch)*9 + ofs]);
    }
    wp1[i] = v;
  }
  for (int i = tid; i < 16*584; i += 256) {
    int oc = i / 584, k = i % 584;
    ushort v = 0;
    if (k < 576) {
      int ofs = k >> 6, ch = k & 63;
      if (oc < 12 && ch < 48) v = f2b(c2w[(oc*48 + ch)*9 + ofs]);
    }
    wp2[i] = v;
  }
}

// ---------------- conv1 MFMA: 3x3 12->48, relu^2, bf16 channel-last out ----------------
// in: lnb_b planar bf16 [2][12][1024][512]; out: t[2][1024][512][48]
__global__ __launch_bounds__(256)
void k_c1m(const ushort* __restrict__ in, const ushort* __restrict__ Wp,
           const float* __restrict__ bias, ushort* __restrict__ out)
{
  __shared__ __align__(16) ushort Wl[48*168];     // 16128 B
  __shared__ __align__(16) ushort Xl[4*136*16];   // 17408 B (row3 + ch-pad zeroed)
  __shared__ float Bs[48];
  const int b = blockIdx.z, ybase = blockIdx.y*8, x0 = blockIdx.x*128;
  const int tid = threadIdx.x, lane = tid & 63, wv = tid >> 6;
  const int lm = lane & 15, lg = lane >> 4;
  const int hl = lg >> 1, cbs = lg & 1;

  for (int i = tid; i < 48*168; i += 256) Wl[i] = Wp[i];
  for (int i = tid; i < 4*136*16; i += 256) Xl[i] = 0;
  if (tid < 48) Bs[tid] = bias[tid];

  for (int y8 = 0; y8 < 8; y8++) {
    int y = ybase + y8;
    __syncthreads();                       // prev compute done / first: init done
    // stage rows 0..2, ch 0..11, cols 0..135 (tile col c <-> x = x0-4+c)
    for (int i = tid; i < 3*34*12; i += 256) {
      int ch = i % 12, cc = (i/12) % 34, r = i/(12*34);
      int sy = y + r - 1, sx = x0 - 4 + cc*4;
      ushort4 v = (ushort4){0,0,0,0};
      if ((unsigned)sy < 1024u) {
        const ushort* p = in + ((size_t)(b*12+ch)*1024 + sy)*512 + sx;
        if (sx >= 0 && sx <= 508) v = *(const ushort4*)p;
        else {
          ushort tv[4] = {0,0,0,0};
          #pragma unroll
          for (int u = 0; u < 4; u++) { int xx = sx+u; if ((unsigned)xx < 512u) tv[u] = p[u]; }
          v = (ushort4){tv[0],tv[1],tv[2],tv[3]};
        }
      }
      int cb = ch >> 3, ce = ch & 7;
      #pragma unroll
      for (int u = 0; u < 4; u++) {
        int col = cc*4 + u;
        Xl[((r*136 + col) << 4) + ((cb ^ (col & 1)) << 3) + ce] = ((const ushort*)&v)[u];
      }
    }
    __syncthreads();

    f4_t acc[3][2];
    #pragma unroll
    for (int i = 0; i < 3; i++) { acc[i][0] = (f4_t){0,0,0,0}; acc[i][1] = (f4_t){0,0,0,0}; }
    #pragma unroll
    for (int s = 0; s < 5; s++) {
      bf8_t af[3];
      #pragma unroll
      for (int mf = 0; mf < 3; mf++)
        af[mf] = *(const bf8_t*)&Wl[(mf*16 + lm)*168 + s*32 + lg*8];
      int ofs = 2*s + hl;
      int dy = ofs / 3, dx = ofs - dy*3;     // ofs==9 -> dy=3 (zero row), dx=0
      #pragma unroll
      for (int nf = 0; nf < 2; nf++) {
        int col = (wv*2 + nf)*16 + lm + dx + 3;
        bf8_t bf = *(const bf8_t*)&Xl[((dy*136 + col) << 4) + ((cbs ^ (col & 1)) << 3)];
        #pragma unroll
        for (int mf = 0; mf < 3; mf++)
          acc[mf][nf] = __builtin_amdgcn_mfma_f32_16x16x32_bf16(af[mf], bf, acc[mf][nf], 0, 0, 0);
      }
    }
    // epilogue: bias + relu^2, channel-last bf16
    #pragma unroll
    for (int nf = 0; nf < 2; nf++) {
      int p = (wv*2 + nf)*16 + lm;
      ushort* op = out + (((size_t)(b*1024 + y)*512) + x0 + p)*48;
      #pragma unroll
      for (int mf = 0; mf < 3; mf++) {
        int oc0 = mf*16 + lg*4;
        f4_t a = acc[mf][nf];
        float r0 = fmaxf(a.x + Bs[oc0+0], 0.f);
        float r1 = fmaxf(a.y + Bs[oc0+1], 0.f);
        float r2 = fmaxf(a.z + Bs[oc0+2], 0.f);
        float r3 = fmaxf(a.w + Bs[oc0+3], 0.f);
        ushort4 o;
        o.x = f2b(r0*r0); o.y = f2b(r1*r1); o.z = f2b(r2*r2); o.w = f2b(r3*r3);
        *(ushort4*)&op[oc0] = o;
      }
    }
  }
}

// ---------------- conv2 MFMA: 3x3 48->12, +bias +residual, dual planar fp32 out ----------------
__global__ __launch_bounds__(256)
void k_c2m(const ushort* __restrict__ tin, const ushort* __restrict__ Wp,
           const float* __restrict__ bias, const float* __restrict__ h1,
           float* __restrict__ out0, float* __restrict__ out1)
{
  __shared__ __align__(16) ushort Wl[16*584];     // 18688 B
  __shared__ __align__(16) ushort Xl[3*132*64];   // 50688 B (ch-pad zeroed)
  __shared__ float Bs[12];
  const int b = blockIdx.z, ybase = blockIdx.y*8, x0 = blockIdx.x*128;
  const int tid = threadIdx.x, lane = tid & 63, wv = tid >> 6;
  const int lm = lane & 15, lg = lane >> 4;

  for (int i = tid; i < 16*584; i += 256) Wl[i] = Wp[i];
  for (int i = tid; i < 3*132*64; i += 256) Xl[i] = 0;
  if (tid < 12) Bs[tid] = bias[tid];

  for (int y8 = 0; y8 < 8; y8++) {
    int y = ybase + y8;
    __syncthreads();
    // stage rows 0..2 x cols 0..131 x ch-chunks 0..5 (tile col c <-> x = x0-1+c)
    for (int i = tid; i < 3*132*6; i += 256) {
      int ck = i % 6, col = (i/6) % 132, r = i/(6*132);
      int sy = y + r - 1, sx = x0 + col - 1;
      uint4 v = (uint4){0u,0u,0u,0u};
      if ((unsigned)sy < 1024u && (unsigned)sx < 512u)
        v = *(const uint4*)&tin[(((size_t)(b*1024 + sy)*512 + sx)*48) + ck*8];
      *(uint4*)&Xl[((r*132 + col) << 6) + ((ck ^ (col & 7)) << 3)] = v;
    }
    __syncthreads();

    f4_t acc[2];
    acc[0] = (f4_t){0,0,0,0}; acc[1] = (f4_t){0,0,0,0};
    #pragma unroll
    for (int s = 0; s < 18; s++) {
      bf8_t af = *(const bf8_t*)&Wl[lm*584 + s*32 + lg*8];
      int ofs = s >> 1;
      int dy = ofs / 3, dx = ofs - dy*3;
      int cb = ((s & 1) << 2) + lg;
      #pragma unroll
      for (int nf = 0; nf < 2; nf++) {
        int col = (wv*2 + nf)*16 + lm + dx;
        bf8_t bf = *(const bf8_t*)&Xl[((dy*132 + col) << 6) + ((cb ^ (col & 7)) << 3)];
        acc[nf] = __builtin_amdgcn_mfma_f32_16x16x32_bf16(af, bf, acc[nf], 0, 0, 0);
      }
    }
    // epilogue: oc = lg*4+reg (<12), planar stores
    if (lg < 3) {
      #pragma unroll
      for (int nf = 0; nf < 2; nf++) {
        int p = x0 + (wv*2 + nf)*16 + lm;
        f4_t a = acc[nf];
        #pragma unroll
        for (int r = 0; r < 4; r++) {
          int oc = lg*4 + r;
          size_t po = ((size_t)(b*12 + oc)*1024 + y)*512 + p;
          float hv = a[r] + Bs[oc] + h1[po];
          out1[po] = hv;
          out0[((size_t)(b*15 + 3 + oc)*1024 + y)*512 + p] = hv;
        }
      }
    }
  }
}

// ---------------- copy x into out0 channels 0..2 ----------------
__global__ __launch_bounds__(256)
void k_copyx(const float* __restrict__ x, float* __restrict__ out0)
{
  int t = blockIdx.x * 256 + threadIdx.x;   // 2*3*1024*128
  int x4 = (t & 127) * 4;
  int y  = (t >> 7) & 1023;
  int ci = (t >> 17) % 3;
  int b  = t / 393216;
  *(float4*)&out0[(((size_t)b*15 + ci)*FEAT + y)*WDIM + x4] =
      *(const float4*)&x[(((size_t)b*3 + ci)*FEAT + y)*WDIM + x4];
}

extern "C" void kernel_launch(void* const* d_in, const int* in_sizes, int n_in,
                              void* d_out, int out_size, void* d_ws, size_t ws_size,
                              hipStream_t stream)
{
  const float* x       = (const float*)d_in[0];
  const float* embed_w = (const float*)d_in[1];
  const float* embed_b = (const float*)d_in[2];
  const float* ln1_w   = (const float*)d_in[3];
  const float* ln1_b   = (const float*)d_in[4];
  const float* q_dw    = (const float*)d_in[5];
  const float* q_pw    = (const float*)d_in[6];
  const float* k_dw    = (const float*)d_in[7];
  const float* k_pw    = (const float*)d_in[8];
  const float* v_dw    = (const float*)d_in[9];
  const float* v_pw    = (const float*)d_in[10];
  const float* o_pw    = (const float*)d_in[11];
  const float* ln2_w   = (const float*)d_in[12];
  const float* ln2_b   = (const float*)d_in[13];
  const float* c1_w    = (const float*)d_in[14];
  const float* c1_b    = (const float*)d_in[15];
  const float* c2_w    = (const float*)d_in[16];
  const float* c2_b    = (const float*)d_in[17];

  // 14 half-slots (HS floats each) = 7*NB floats = 352 MB.
  // H0,H1 h0 | H2 lnb_b(bf16)/part of lnb | H2,H3 lnb fp32 | H4,H5 dwq->pwbq,pwbk->Wp/t? see below
  // Timeline: dwq(H4,5) dwk(H6,7) dwv(H8,9) -> tr3 -> dwtq(H10) dwtk(H11) dwtv(H12)
  //   cvt: pwbq(H4) pwbk(H5) pwbv(H6) pwbo(H7); Qb(H8) Kb(H9) Vb(H13)
  //   probs(H10,H11), attt(H12); after o-proj: Wp(H4), lnb_b(H2), t(H8..H11)
  float* ws = (float*)d_ws;
  float*  h0   = ws + 0*HS;
  float*  lnb  = ws + 2*HS;
  float*  dwq  = ws + 4*HS;
  float*  dwk  = ws + 6*HS;
  float*  dwv  = ws + 8*HS;
  ushort* dwtq = (ushort*)(ws + 10*HS);
  ushort* dwtk = (ushort*)(ws + 11*HS);
  ushort* dwtv = (ushort*)(ws + 12*HS);
  ushort* pwbq = (ushort*)(ws + 4*HS);
  ushort* pwbk = (ushort*)(ws + 5*HS);
  ushort* pwbv = (ushort*)(ws + 6*HS);
  ushort* pwbo = (ushort*)(ws + 7*HS);
  ushort* Qb   = (ushort*)(ws + 8*HS);
  ushort* Kb   = (ushort*)(ws + 9*HS);
  ushort* Vb   = (ushort*)(ws + 13*HS);
  ushort* probs= (ushort*)(ws + 10*HS);
  ushort* attt = (ushort*)(ws + 12*HS);
  ushort* Wp1  = (ushort*)(ws + 4*HS);        // after o-proj
  ushort* Wp2  = Wp1 + 48*168;
  ushort* lnb_b= (ushort*)(ws + 2*HS);
  ushort* tcl  = (ushort*)(ws + 8*HS);        // t channel-last [2][1024][512][48]

  float* out0 = (float*)d_out;                       // (2,15,1024,512)
  float* out1 = out0 + (size_t)2*15*FEAT*WDIM;       // (2,12,1024,512)
  float* qk   = out1 + NB;                           // (2,12,4,512,512)

  k_embed<<<1024, 256, 0, stream>>>(x, embed_w, embed_b, h0);
  k_ln<<<dim3(8, 24), 256, 0, stream>>>(h0, ln1_w, ln1_b, lnb);
  k_dw3<<<dim3(8, 256, 24), 256, 0, stream>>>(lnb, q_dw, k_dw, v_dw, dwq, dwk, dwv);
  k_tr3<<<dim3(8, 16, 24), 256, 0, stream>>>(dwq, dwk, dwv, dwtq, dwtk, dwtv);
  k_cvt<<<6144, 256, 0, stream>>>(q_pw, pwbq);
  k_cvt<<<6144, 256, 0, stream>>>(k_pw, pwbk);
  k_cvt<<<6144, 256, 0, stream>>>(v_pw, pwbv);
  k_cvt<<<6144, 256, 0, stream>>>(o_pw, pwbo);
  mgemm<0><<<dim3(4, 2, 96), 256, 0, stream>>>(pwbq, dwtq, Qb);
  mgemm<0><<<dim3(4, 2, 96), 256, 0, stream>>>(pwbk, dwtk, Kb);
  mgemm<4><<<dim3(4, 2, 96), 256, 0, stream>>>(pwbv, dwtv, Vb);
  mgemm<1><<<dim3(4, 4, 96), 256, 0, stream>>>(Qb, Kb, qk);
  k_softmax<<<12288, 256, 0, stream>>>(qk, probs);
  mgemm<2><<<dim3(2, 4, 96), 256, 0, stream>>>(probs, Vb, attt);
  mgemm<3><<<dim3(4, 8, 24), 256, 0, stream>>>(pwbo, attt, (void*)h0);
  // FFN (MFMA implicit GEMM)
  k_pack<<<1, 256, 0, stream>>>(c1_w, c2_w, Wp1, Wp2);
  k_ln_b<<<dim3(8, 24), 256, 0, stream>>>(h0, ln2_w, ln2_b, lnb_b);
  k_c1m<<<dim3(4, 128, 2), 256, 0, stream>>>(lnb_b, Wp1, c1_b, tcl);
  k_c2m<<<dim3(4, 128, 2), 256, 0, stream>>>(tcl, Wp2, c2_b, h0, out0, out1);
  k_copyx<<<3072, 256, 0, stream>>>(x, out0);
}

// Round 5
// 1199.474 us; speedup vs baseline: 2.6403x; 1.1148x over previous
//
#include <hip/hip_runtime.h>
#include <math.h>

static constexpr int FEAT = 1024;
static constexpr int WDIM = 512;
static constexpr size_t PL = (size_t)FEAT * WDIM;      // 524288 per (b,c) plane
static constexpr size_t NB = (size_t)2 * 12 * PL;      // 12582912 full tensor
static constexpr size_t HS = NB / 2;                   // floats per half-slot

typedef __attribute__((ext_vector_type(8))) short bf8_t;   // 8 bf16 (4 VGPR)
typedef __attribute__((ext_vector_type(4))) float f4_t;

__device__ __forceinline__ ushort f2b(float f) {
  union { float f; unsigned u; } x; x.f = f;
  unsigned u = x.u;
  return (ushort)((u + 0x7FFFu + ((u >> 16) & 1u)) >> 16);   // RNE
}

#define GLL16(g, l) __builtin_amdgcn_global_load_lds(                         \
    (const __attribute__((address_space(1))) void*)(g),                       \
    (__attribute__((address_space(3))) void*)(l), 16, 0, 0)

// ---------------- embed: 1x1 conv 3->12 ----------------
__global__ __launch_bounds__(256)
void k_embed(const float* __restrict__ x, const float* __restrict__ ew,
             const float* __restrict__ eb, float* __restrict__ h0)
{
  int t = blockIdx.x * 256 + threadIdx.x;      // 2*1024*128
  int x4 = (t & 127) * 4;
  int y  = (t >> 7) & 1023;
  int b  = t >> 17;
  float4 xi0 = *(const float4*)&x[(((size_t)b*3+0)*FEAT + y)*WDIM + x4];
  float4 xi1 = *(const float4*)&x[(((size_t)b*3+1)*FEAT + y)*WDIM + x4];
  float4 xi2 = *(const float4*)&x[(((size_t)b*3+2)*FEAT + y)*WDIM + x4];
  #pragma unroll
  for (int c = 0; c < 12; c++) {
    float w0 = ew[c*3], w1 = ew[c*3+1], w2 = ew[c*3+2], bb = eb[c];
    float4 o;
    o.x = fmaf(xi0.x, w0, fmaf(xi1.x, w1, fmaf(xi2.x, w2, bb)));
    o.y = fmaf(xi0.y, w0, fmaf(xi1.y, w1, fmaf(xi2.y, w2, bb)));
    o.z = fmaf(xi0.z, w0, fmaf(xi1.z, w1, fmaf(xi2.z, w2, bb)));
    o.w = fmaf(xi0.w, w0, fmaf(xi1.w, w1, fmaf(xi2.w, w2, bb)));
    *(float4*)&h0[(((size_t)b*12+c)*FEAT + y)*WDIM + x4] = o;
  }
}

// ---------------- layernorm over feature axis (h), per (b,c,w), fp32 out ----------------
__global__ __launch_bounds__(256)
void k_ln(const float* __restrict__ in, const float* __restrict__ w,
          const float* __restrict__ bia, float* __restrict__ out)
{
  int bc = blockIdx.y; int c = bc % 12;
  int w0 = blockIdx.x * 64;
  int tx = threadIdx.x & 63, ty = threadIdx.x >> 6;   // 64 x 4
  const float* base = in + (size_t)bc*PL + w0;
  float s = 0.f, ss = 0.f;
  for (int h = ty; h < FEAT; h += 4) {
    float v = base[(size_t)h*WDIM + tx];
    s += v; ss = fmaf(v, v, ss);
  }
  __shared__ float S1[4][64], S2[4][64];
  S1[ty][tx] = s; S2[ty][tx] = ss;
  __syncthreads();
  if (ty == 0) {
    float t1 = S1[0][tx]+S1[1][tx]+S1[2][tx]+S1[3][tx];
    float t2 = S2[0][tx]+S2[1][tx]+S2[2][tx]+S2[3][tx];
    float mu = t1 * (1.0f/1024.0f);
    float var = t2 * (1.0f/1024.0f) - mu*mu;
    S1[0][tx] = mu; S2[0][tx] = rsqrtf(var + 1e-8f);
  }
  __syncthreads();
  float mu = S1[0][tx], ri = S2[0][tx];
  float* ob = out + (size_t)bc*PL + w0;
  for (int h = ty; h < FEAT; h += 4) {
    float v = base[(size_t)h*WDIM + tx];
    ob[(size_t)h*WDIM + tx] = (v - mu) * ri * w[c*FEAT + h] + bia[c*FEAT + h];
  }
}

// ---------------- layernorm variant: bf16 planar out (feeds conv1) ----------------
__global__ __launch_bounds__(256)
void k_ln_b(const float* __restrict__ in, const float* __restrict__ w,
            const float* __restrict__ bia, ushort* __restrict__ out)
{
  int bc = blockIdx.y; int c = bc % 12;
  int w0 = blockIdx.x * 64;
  int tx = threadIdx.x & 63, ty = threadIdx.x >> 6;
  const float* base = in + (size_t)bc*PL + w0;
  float s = 0.f, ss = 0.f;
  for (int h = ty; h < FEAT; h += 4) {
    float v = base[(size_t)h*WDIM + tx];
    s += v; ss = fmaf(v, v, ss);
  }
  __shared__ float S1[4][64], S2[4][64];
  S1[ty][tx] = s; S2[ty][tx] = ss;
  __syncthreads();
  if (ty == 0) {
    float t1 = S1[0][tx]+S1[1][tx]+S1[2][tx]+S1[3][tx];
    float t2 = S2[0][tx]+S2[1][tx]+S2[2][tx]+S2[3][tx];
    float mu = t1 * (1.0f/1024.0f);
    float var = t2 * (1.0f/1024.0f) - mu*mu;
    S1[0][tx] = mu; S2[0][tx] = rsqrtf(var + 1e-8f);
  }
  __syncthreads();
  float mu = S1[0][tx], ri = S2[0][tx];
  ushort* ob = out + (size_t)bc*PL + w0;
  for (int h = ty; h < FEAT; h += 4) {
    float v = base[(size_t)h*WDIM + tx];
    ob[(size_t)h*WDIM + tx] = f2b((v - mu) * ri * w[c*FEAT + h] + bia[c*FEAT + h]);
  }
}

// ---------------- fused 9x9 depthwise conv (q,k,v) + transpose + bf16 ----------------
// in: lnb fp32 [bc][h=1024][w=512]; out: bf16 [bc][w=512][h=1024] x3
// block: 64x64 output tile; wave wv_ owns 16 y-rows; dx-outer register-weight loop.
__global__ __launch_bounds__(256)
void k_dw3t(const float* __restrict__ in, const float* __restrict__ wq,
            const float* __restrict__ wk, const float* __restrict__ wvv,
            ushort* __restrict__ oq, ushort* __restrict__ ok2, ushort* __restrict__ ov)
{
  __shared__ float tile[72*72];       // 20736 B, reused as ushort T[64][72] for transpose
  __shared__ float wsm[3][81];
  const int bc = blockIdx.z, c = bc % 12;
  const int y0 = blockIdx.y * 64, x0 = blockIdx.x * 64;
  const int tid = threadIdx.x, lane = tid & 63, wv_ = tid >> 6;
  const float* base = in + (size_t)bc*PL;

  for (int i = tid; i < 1296; i += 256) {      // 72 rows x 18 float4
    int r = i / 18, c4 = (i % 18) * 4;
    int gy = y0 - 4 + r, gx = x0 - 4 + c4;
    float4 v = {0.f,0.f,0.f,0.f};
    if ((unsigned)gy < 1024u && (unsigned)gx < 512u)
      v = *(const float4*)&base[(size_t)gy*512 + gx];
    *(float4*)&tile[r*72 + c4] = v;
  }
  if (tid < 81) { wsm[0][tid] = wq[c*81+tid]; wsm[1][tid] = wk[c*81+tid]; wsm[2][tid] = wvv[c*81+tid]; }
  __syncthreads();

  float aq[16] = {}, ak[16] = {}, av[16] = {};
  #pragma unroll 1
  for (int dx = 0; dx < 9; dx++) {
    float wq9[9], wk9[9], wv9[9];
    #pragma unroll
    for (int dy = 0; dy < 9; dy++) {
      wq9[dy] = wsm[0][dy*9+dx]; wk9[dy] = wsm[1][dy*9+dx]; wv9[dy] = wsm[2][dy*9+dx];
    }
    const float* col = &tile[(wv_*16)*72 + lane + dx];
    #pragma unroll
    for (int r = 0; r < 24; r++) {
      float v = col[r*72];
      int dylo = (r > 15) ? (r - 15) : 0;
      int dyhi = (r < 8) ? r : 8;
      #pragma unroll
      for (int dy = 0; dy < 9; dy++) {
        if (dy >= dylo && dy <= dyhi) {
          aq[r-dy] = fmaf(v, wq9[dy], aq[r-dy]);
          ak[r-dy] = fmaf(v, wk9[dy], ak[r-dy]);
          av[r-dy] = fmaf(v, wv9[dy], av[r-dy]);
        }
      }
    }
  }

  // transpose epilogue: T[x][y] (stride 72 ushorts = 144B, 16B aligned rows)
  ushort* T = (ushort*)tile;
#define DW_EMIT(ACC, OUT)                                                     \
  {                                                                           \
    __syncthreads();                                                          \
    uint pk[8];                                                               \
    _Pragma("unroll")                                                         \
    for (int u = 0; u < 8; u++)                                               \
      pk[u] = (uint)f2b(ACC[2*u]) | ((uint)f2b(ACC[2*u+1]) << 16);            \
    uint4* dst = (uint4*)&T[lane*72 + wv_*16];                                \
    dst[0] = make_uint4(pk[0],pk[1],pk[2],pk[3]);                             \
    dst[1] = make_uint4(pk[4],pk[5],pk[6],pk[7]);                             \
    __syncthreads();                                                          \
    ushort* op = OUT + (size_t)bc*PL;                                         \
    _Pragma("unroll")                                                         \
    for (int it = 0; it < 2; it++) {                                          \
      int idx = it*256 + tid;                                                 \
      int xr = idx >> 3, y8 = (idx & 7) * 8;                                  \
      uint4 vv = *(uint4*)&T[xr*72 + y8];                                     \
      *(uint4*)&op[(size_t)(x0+xr)*1024 + y0 + y8] = vv;                      \
    }                                                                         \
  }
  DW_EMIT(aq, oq)
  DW_EMIT(ak, ok2)
  DW_EMIT(av, ov)
#undef DW_EMIT
}

// ---------------- fp32 -> bf16 convert, 4 tensors (outs contiguous) ----------------
__global__ __launch_bounds__(256)
void k_cvt4(const float* __restrict__ p0, const float* __restrict__ p1,
            const float* __restrict__ p2, const float* __restrict__ p3,
            ushort* __restrict__ out)
{
  const float* ins[4] = {p0, p1, p2, p3};
  const float* in = ins[blockIdx.y];
  size_t i = ((size_t)blockIdx.x * 256 + threadIdx.x) * 8;
  ushort* o = out + (size_t)blockIdx.y * NB + i;
  float4 v0 = *(const float4*)&in[i];
  float4 v1 = *(const float4*)&in[i+4];
  union { ushort u[8]; uint4 v; } t;
  t.u[0]=f2b(v0.x); t.u[1]=f2b(v0.y); t.u[2]=f2b(v0.z); t.u[3]=f2b(v0.w);
  t.u[4]=f2b(v1.x); t.u[5]=f2b(v1.y); t.u[6]=f2b(v1.z); t.u[7]=f2b(v1.w);
  *(uint4*)o = t.v;
}

// ---------------- row softmax (rows of 512), one wave per row, bf16 out ----------------
__global__ __launch_bounds__(256)
void k_softmax(const float* __restrict__ qk, ushort* __restrict__ probs)
{
  int wave = threadIdx.x >> 6, lane = threadIdx.x & 63;
  size_t row = (size_t)blockIdx.x * 4 + wave;
  const float* r = qk + row * 512;
  float v[8];
  float m = -1e30f;
  #pragma unroll
  for (int j = 0; j < 8; j++) { v[j] = r[lane + 64*j]; m = fmaxf(m, v[j]); }
  #pragma unroll
  for (int o = 32; o; o >>= 1) m = fmaxf(m, __shfl_xor(m, o));
  float s = 0.f;
  #pragma unroll
  for (int j = 0; j < 8; j++) { v[j] = expf(v[j] - m); s += v[j]; }
  #pragma unroll
  for (int o = 32; o; o >>= 1) s += __shfl_xor(s, o);
  float inv = 1.0f / s;
  ushort* p = probs + row * 512;
  #pragma unroll
  for (int j = 0; j < 8; j++) p[lane + 64*j] = f2b(v[j] * inv);
}

// ---------------- MFMA bf16 GEMM, fragment-ordered LDS, 128x128 tile ----------------
// MODE 0: proj Q AND K (z<96: Q; z>=96: K, buffers offset by one tensor). RoPE fused.
// MODE 4: proj V -> Vb[z][d][w]. MODE 1: QK^T/32 -> qk fp32. MODE 2: PV -> attt.
// MODE 3: OPROJ += into h0.
template<int MODE>
__global__ __launch_bounds__(256)
void mgemm(const ushort* __restrict__ Ab, const ushort* __restrict__ Bb,
           void* __restrict__ Cb)
{
  constexpr int K   = (MODE==1) ? 256 : ((MODE==2) ? 512 : 1024);
  constexpr int LDA = (MODE==1) ? 256 : ((MODE==2) ? 512 : 1024);
  constexpr int LDB = LDA;

  const int z = blockIdx.z;
  const ushort* A; const ushort* B;
  int zz = z; size_t toff = 0;
  if constexpr (MODE==0 || MODE==4) {
    if constexpr (MODE==0) { int t = (z >= 96); zz = z - 96*t; toff = (size_t)t * NB; }
    int bc = zz >> 2, head = zz & 3, c = bc % 12;
    A = Ab + toff + ((size_t)c*1024 + head*256)*1024;
    B = Bb + toff + (size_t)bc*524288;
  } else if constexpr (MODE==1) {
    A = Ab + (size_t)z*131072; B = Bb + (size_t)z*131072;
  } else if constexpr (MODE==2) {
    A = Ab + (size_t)z*262144; B = Bb + (size_t)z*131072;
  } else {
    int c = z % 12;
    A = Ab + (size_t)c*1048576;
    B = Bb + (size_t)z*524288;
  }

  const int m0 = blockIdx.y * 128, n0 = blockIdx.x * 128;
  const int tid = threadIdx.x, lane = tid & 63, wv = tid >> 6;
  const int wr = wv >> 1, wc = wv & 1;
  const int lm = lane & 15, lg = lane >> 4;

  __shared__ __align__(16) ushort Alds[4096];
  __shared__ __align__(16) ushort Blds[4096];

  const ushort* gA0 = A + (size_t)(m0 + (2*wv)*16 + lm)*LDA + 8*lg;
  const ushort* gA1 = gA0 + (size_t)16*LDA;
  const ushort* gB0 = B + (size_t)(n0 + (2*wv)*16 + lm)*LDB + 8*lg;
  const ushort* gB1 = gB0 + (size_t)16*LDB;
  ushort* lA0 = &Alds[(2*wv)*512]; ushort* lA1 = lA0 + 512;
  ushort* lB0 = &Blds[(2*wv)*512]; ushort* lB1 = lB0 + 512;

  f4_t acc[4][4];
  #pragma unroll
  for (int i = 0; i < 4; i++)
    #pragma unroll
    for (int j = 0; j < 4; j++) acc[i][j] = (f4_t){0.f, 0.f, 0.f, 0.f};

  for (int k0 = 0; k0 < K; k0 += 32) {
    GLL16(gA0 + k0, lA0); GLL16(gA1 + k0, lA1);
    GLL16(gB0 + k0, lB0); GLL16(gB1 + k0, lB1);
    __syncthreads();
    bf8_t fa[4], fb[4];
    #pragma unroll
    for (int i = 0; i < 4; i++) fa[i] = *(const bf8_t*)&Alds[(wr*4+i)*512 + lane*8];
    #pragma unroll
    for (int j = 0; j < 4; j++) fb[j] = *(const bf8_t*)&Blds[(wc*4+j)*512 + lane*8];
    #pragma unroll
    for (int i = 0; i < 4; i++)
      #pragma unroll
      for (int j = 0; j < 4; j++)
        acc[i][j] = __builtin_amdgcn_mfma_f32_16x16x32_bf16(fa[i], fb[j], acc[i][j], 0, 0, 0);
    __syncthreads();
  }

  if constexpr (MODE==0) {          // Qb/Kb [zz][w][d] + RoPE
    ushort* C = (ushort*)Cb + toff + (size_t)zz*131072;
    #pragma unroll
    for (int j = 0; j < 4; j++) {
      int w = n0 + wc*64 + j*16 + lm;
      #pragma unroll
      for (int i = 0; i < 4; i++) {
        int d0 = m0 + wr*64 + i*16 + lg*4;
        int p0 = d0 >> 1;
        float inv0 = expf(-(float)p0 * 0.07195578432833848f);
        float inv1 = inv0 * 0.9305720409297794f;
        float s0, c0, s1, c1;
        sincosf((float)w * inv0, &s0, &c0);
        sincosf((float)w * inv1, &s1, &c1);
        f4_t a = acc[i][j];
        ushort4 o;
        o.x = f2b(a.x*c0 - a.y*s0);
        o.y = f2b(a.y*c0 + a.x*s0);
        o.z = f2b(a.z*c1 - a.w*s1);
        o.w = f2b(a.w*c1 + a.z*s1);
        *(ushort4*)&C[(size_t)w*256 + d0] = o;
      }
    }
  } else if constexpr (MODE==4) {   // Vb[z][d][w]
    ushort* C = (ushort*)Cb + (size_t)z*131072;
    #pragma unroll
    for (int i = 0; i < 4; i++) {
      int d0 = m0 + wr*64 + i*16 + lg*4;
      #pragma unroll
      for (int j = 0; j < 4; j++) {
        int w = n0 + wc*64 + j*16 + lm;
        f4_t a = acc[i][j];
        C[(size_t)(d0+0)*512 + w] = f2b(a.x);
        C[(size_t)(d0+1)*512 + w] = f2b(a.y);
        C[(size_t)(d0+2)*512 + w] = f2b(a.z);
        C[(size_t)(d0+3)*512 + w] = f2b(a.w);
      }
    }
  } else if constexpr (MODE==1) {   // qk fp32, *1/32
    float* C = (float*)Cb + (size_t)z*262144;
    #pragma unroll
    for (int i = 0; i < 4; i++) {
      int q0 = m0 + wr*64 + i*16 + lg*4;
      #pragma unroll
      for (int j = 0; j < 4; j++) {
        int kc = n0 + wc*64 + j*16 + lm;
        f4_t a = acc[i][j];
        C[(size_t)(q0+0)*512 + kc] = a.x * 0.03125f;
        C[(size_t)(q0+1)*512 + kc] = a.y * 0.03125f;
        C[(size_t)(q0+2)*512 + kc] = a.z * 0.03125f;
        C[(size_t)(q0+3)*512 + kc] = a.w * 0.03125f;
      }
    }
  } else if constexpr (MODE==2) {   // attt[bc][q][head*256+d]
    ushort* C = (ushort*)Cb + (size_t)(z>>2)*524288 + (size_t)(z&3)*256;
    #pragma unroll
    for (int i = 0; i < 4; i++) {
      int q0 = m0 + wr*64 + i*16 + lg*4;
      #pragma unroll
      for (int j = 0; j < 4; j++) {
        int d = n0 + wc*64 + j*16 + lm;
        f4_t a = acc[i][j];
        C[(size_t)(q0+0)*1024 + d] = f2b(a.x);
        C[(size_t)(q0+1)*1024 + d] = f2b(a.y);
        C[(size_t)(q0+2)*1024 + d] = f2b(a.z);
        C[(size_t)(q0+3)*1024 + d] = f2b(a.w);
      }
    }
  } else {                          // MODE3: h0 += , fp32 in place
    float* C = (float*)Cb + (size_t)z*524288;
    #pragma unroll
    for (int i = 0; i < 4; i++) {
      int f0 = m0 + wr*64 + i*16 + lg*4;
      #pragma unroll
      for (int j = 0; j < 4; j++) {
        int w = n0 + wc*64 + j*16 + lm;
        f4_t a = acc[i][j];
        C[(size_t)(f0+0)*512 + w] += a.x;
        C[(size_t)(f0+1)*512 + w] += a.y;
        C[(size_t)(f0+2)*512 + w] += a.z;
        C[(size_t)(f0+3)*512 + w] += a.w;
      }
    }
  }
}

// ---------------- pack FFN conv weights to MFMA layouts (bf16, zero-padded) ----------------
__global__ __launch_bounds__(256)
void k_pack(const float* __restrict__ c1w, const float* __restrict__ c2w,
            ushort* __restrict__ wp1, ushort* __restrict__ wp2)
{
  int tid = threadIdx.x;
  for (int i = tid; i < 48*168; i += 256) {
    int oc = i / 168, k = i % 168;
    ushort v = 0;
    if (k < 160) {
      int ofs = k >> 4, ch = k & 15;
      if (ofs < 9 && ch < 12) v = f2b(c1w[(oc*12 + ch)*9 + ofs]);
    }
    wp1[i] = v;
  }
  for (int i = tid; i < 16*584; i += 256) {
    int oc = i / 584, k = i % 584;
    ushort v = 0;
    if (k < 576) {
      int ofs = k >> 6, ch = k & 63;
      if (oc < 12 && ch < 48) v = f2b(c2w[(oc*48 + ch)*9 + ofs]);
    }
    wp2[i] = v;
  }
}

// ---------------- conv1 MFMA: 3x3 12->48, relu^2, bf16 channel-last out ----------------
__global__ __launch_bounds__(256)
void k_c1m(const ushort* __restrict__ in, const ushort* __restrict__ Wp,
           const float* __restrict__ bias, ushort* __restrict__ out)
{
  __shared__ __align__(16) ushort Wl[48*168];
  __shared__ __align__(16) ushort Xl[4*136*16];
  __shared__ float Bs[48];
  const int b = blockIdx.z, ybase = blockIdx.y*8, x0 = blockIdx.x*128;
  const int tid = threadIdx.x, lane = tid & 63, wv = tid >> 6;
  const int lm = lane & 15, lg = lane >> 4;
  const int hl = lg >> 1, cbs = lg & 1;

  for (int i = tid; i < 48*168; i += 256) Wl[i] = Wp[i];
  for (int i = tid; i < 4*136*16; i += 256) Xl[i] = 0;
  if (tid < 48) Bs[tid] = bias[tid];

  for (int y8 = 0; y8 < 8; y8++) {
    int y = ybase + y8;
    __syncthreads();
    for (int i = tid; i < 3*34*12; i += 256) {
      int ch = i % 12, cc = (i/12) % 34, r = i/(12*34);
      int sy = y + r - 1, sx = x0 - 4 + cc*4;
      ushort4 v = (ushort4){0,0,0,0};
      if ((unsigned)sy < 1024u) {
        const ushort* p = in + ((size_t)(b*12+ch)*1024 + sy)*512 + sx;
        if (sx >= 0 && sx <= 508) v = *(const ushort4*)p;
        else {
          ushort tv[4] = {0,0,0,0};
          #pragma unroll
          for (int u = 0; u < 4; u++) { int xx = sx+u; if ((unsigned)xx < 512u) tv[u] = p[u]; }
          v = (ushort4){tv[0],tv[1],tv[2],tv[3]};
        }
      }
      int cb = ch >> 3, ce = ch & 7;
      #pragma unroll
      for (int u = 0; u < 4; u++) {
        int col = cc*4 + u;
        Xl[((r*136 + col) << 4) + ((cb ^ (col & 1)) << 3) + ce] = ((const ushort*)&v)[u];
      }
    }
    __syncthreads();

    f4_t acc[3][2];
    #pragma unroll
    for (int i = 0; i < 3; i++) { acc[i][0] = (f4_t){0,0,0,0}; acc[i][1] = (f4_t){0,0,0,0}; }
    #pragma unroll
    for (int s = 0; s < 5; s++) {
      bf8_t af[3];
      #pragma unroll
      for (int mf = 0; mf < 3; mf++)
        af[mf] = *(const bf8_t*)&Wl[(mf*16 + lm)*168 + s*32 + lg*8];
      int ofs = 2*s + hl;
      int dy = ofs / 3, dx = ofs - dy*3;
      #pragma unroll
      for (int nf = 0; nf < 2; nf++) {
        int col = (wv*2 + nf)*16 + lm + dx + 3;
        bf8_t bf = *(const bf8_t*)&Xl[((dy*136 + col) << 4) + ((cbs ^ (col & 1)) << 3)];
        #pragma unroll
        for (int mf = 0; mf < 3; mf++)
          acc[mf][nf] = __builtin_amdgcn_mfma_f32_16x16x32_bf16(af[mf], bf, acc[mf][nf], 0, 0, 0);
      }
    }
    #pragma unroll
    for (int nf = 0; nf < 2; nf++) {
      int p = (wv*2 + nf)*16 + lm;
      ushort* op = out + (((size_t)(b*1024 + y)*512) + x0 + p)*48;
      #pragma unroll
      for (int mf = 0; mf < 3; mf++) {
        int oc0 = mf*16 + lg*4;
        f4_t a = acc[mf][nf];
        float r0 = fmaxf(a.x + Bs[oc0+0], 0.f);
        float r1 = fmaxf(a.y + Bs[oc0+1], 0.f);
        float r2 = fmaxf(a.z + Bs[oc0+2], 0.f);
        float r3 = fmaxf(a.w + Bs[oc0+3], 0.f);
        ushort4 o;
        o.x = f2b(r0*r0); o.y = f2b(r1*r1); o.z = f2b(r2*r2); o.w = f2b(r3*r3);
        *(ushort4*)&op[oc0] = o;
      }
    }
  }
}

// ---------------- conv2 MFMA: 3x3 48->12, +bias +residual, dual planar fp32 out ----------------
__global__ __launch_bounds__(256)
void k_c2m(const ushort* __restrict__ tin, const ushort* __restrict__ Wp,
           const float* __restrict__ bias, const float* __restrict__ h1,
           float* __restrict__ out0, float* __restrict__ out1)
{
  __shared__ __align__(16) ushort Wl[16*584];
  __shared__ __align__(16) ushort Xl[3*132*64];
  __shared__ float Bs[12];
  const int b = blockIdx.z, ybase = blockIdx.y*8, x0 = blockIdx.x*128;
  const int tid = threadIdx.x, lane = tid & 63, wv = tid >> 6;
  const int lm = lane & 15, lg = lane >> 4;

  for (int i = tid; i < 16*584; i += 256) Wl[i] = Wp[i];
  for (int i = tid; i < 3*132*64; i += 256) Xl[i] = 0;
  if (tid < 12) Bs[tid] = bias[tid];

  for (int y8 = 0; y8 < 8; y8++) {
    int y = ybase + y8;
    __syncthreads();
    for (int i = tid; i < 3*132*6; i += 256) {
      int ck = i % 6, col = (i/6) % 132, r = i/(6*132);
      int sy = y + r - 1, sx = x0 + col - 1;
      uint4 v = (uint4){0u,0u,0u,0u};
      if ((unsigned)sy < 1024u && (unsigned)sx < 512u)
        v = *(const uint4*)&tin[(((size_t)(b*1024 + sy)*512 + sx)*48) + ck*8];
      *(uint4*)&Xl[((r*132 + col) << 6) + ((ck ^ (col & 7)) << 3)] = v;
    }
    __syncthreads();

    f4_t acc[2];
    acc[0] = (f4_t){0,0,0,0}; acc[1] = (f4_t){0,0,0,0};
    #pragma unroll
    for (int s = 0; s < 18; s++) {
      bf8_t af = *(const bf8_t*)&Wl[lm*584 + s*32 + lg*8];
      int ofs = s >> 1;
      int dy = ofs / 3, dx = ofs - dy*3;
      int cb = ((s & 1) << 2) + lg;
      #pragma unroll
      for (int nf = 0; nf < 2; nf++) {
        int col = (wv*2 + nf)*16 + lm + dx;
        bf8_t bf = *(const bf8_t*)&Xl[((dy*132 + col) << 6) + ((cb ^ (col & 7)) << 3)];
        acc[nf] = __builtin_amdgcn_mfma_f32_16x16x32_bf16(af, bf, acc[nf], 0, 0, 0);
      }
    }
    if (lg < 3) {
      #pragma unroll
      for (int nf = 0; nf < 2; nf++) {
        int p = x0 + (wv*2 + nf)*16 + lm;
        f4_t a = acc[nf];
        #pragma unroll
        for (int r = 0; r < 4; r++) {
          int oc = lg*4 + r;
          size_t po = ((size_t)(b*12 + oc)*1024 + y)*512 + p;
          float hv = a[r] + Bs[oc] + h1[po];
          out1[po] = hv;
          out0[((size_t)(b*15 + 3 + oc)*1024 + y)*512 + p] = hv;
        }
      }
    }
  }
}

// ---------------- copy x into out0 channels 0..2 ----------------
__global__ __launch_bounds__(256)
void k_copyx(const float* __restrict__ x, float* __restrict__ out0)
{
  int t = blockIdx.x * 256 + threadIdx.x;
  int x4 = (t & 127) * 4;
  int y  = (t >> 7) & 1023;
  int ci = (t >> 17) % 3;
  int b  = t / 393216;
  *(float4*)&out0[(((size_t)b*15 + ci)*FEAT + y)*WDIM + x4] =
      *(const float4*)&x[(((size_t)b*3 + ci)*FEAT + y)*WDIM + x4];
}

extern "C" void kernel_launch(void* const* d_in, const int* in_sizes, int n_in,
                              void* d_out, int out_size, void* d_ws, size_t ws_size,
                              hipStream_t stream)
{
  const float* x       = (const float*)d_in[0];
  const float* embed_w = (const float*)d_in[1];
  const float* embed_b = (const float*)d_in[2];
  const float* ln1_w   = (const float*)d_in[3];
  const float* ln1_b   = (const float*)d_in[4];
  const float* q_dw    = (const float*)d_in[5];
  const float* q_pw    = (const float*)d_in[6];
  const float* k_dw    = (const float*)d_in[7];
  const float* k_pw    = (const float*)d_in[8];
  const float* v_dw    = (const float*)d_in[9];
  const float* v_pw    = (const float*)d_in[10];
  const float* o_pw    = (const float*)d_in[11];
  const float* ln2_w   = (const float*)d_in[12];
  const float* ln2_b   = (const float*)d_in[13];
  const float* c1_w    = (const float*)d_in[14];
  const float* c1_b    = (const float*)d_in[15];
  const float* c2_w    = (const float*)d_in[16];
  const float* c2_b    = (const float*)d_in[17];

  // Half-slot map (HS floats each):
  //   H0,H1 h0 | H2,H3 lnb (later lnb_b bf16 in H2) | H4 dwtq->probs.lo->Wp
  //   H5 dwtk->probs.hi | H6 dwtv->attt | H7..H10 pwbq,pwbk,pwbv,pwbo->tcl
  //   H11 Qb | H12 Kb | H13 Vb
  float* ws = (float*)d_ws;
  float*  h0   = ws + 0*HS;
  float*  lnb  = ws + 2*HS;
  ushort* dwtq = (ushort*)(ws + 4*HS);
  ushort* dwtk = (ushort*)(ws + 5*HS);
  ushort* dwtv = (ushort*)(ws + 6*HS);
  ushort* pwbq = (ushort*)(ws + 7*HS);
  ushort* pwbo = (ushort*)(ws + 10*HS);
  ushort* Qb   = (ushort*)(ws + 11*HS);
  ushort* Vb   = (ushort*)(ws + 13*HS);
  ushort* probs= (ushort*)(ws + 4*HS);
  ushort* attt = (ushort*)(ws + 6*HS);
  ushort* Wp1  = (ushort*)(ws + 4*HS);
  ushort* Wp2  = Wp1 + 48*168;
  ushort* lnb_b= (ushort*)(ws + 2*HS);
  ushort* tcl  = (ushort*)(ws + 7*HS);

  float* out0 = (float*)d_out;                       // (2,15,1024,512)
  float* out1 = out0 + (size_t)2*15*FEAT*WDIM;       // (2,12,1024,512)
  float* qk   = out1 + NB;                           // (2,12,4,512,512)

  k_embed<<<1024, 256, 0, stream>>>(x, embed_w, embed_b, h0);
  k_ln<<<dim3(8, 24), 256, 0, stream>>>(h0, ln1_w, ln1_b, lnb);
  // fused depthwise 9x9 + transpose + bf16
  k_dw3t<<<dim3(8, 16, 24), 256, 0, stream>>>(lnb, q_dw, k_dw, v_dw, dwtq, dwtk, dwtv);
  // pw weights -> bf16 (4 tensors, contiguous outputs)
  k_cvt4<<<dim3(6144, 4), 256, 0, stream>>>(q_pw, k_pw, v_pw, o_pw, pwbq);
  // Q and K projections in one launch (RoPE fused); V projection
  mgemm<0><<<dim3(4, 2, 192), 256, 0, stream>>>(pwbq, dwtq, Qb);
  mgemm<4><<<dim3(4, 2, 96), 256, 0, stream>>>((ushort*)(ws + 9*HS), dwtv, Vb);
  // QK^T / 32 -> qk output (fp32)
  mgemm<1><<<dim3(4, 4, 96), 256, 0, stream>>>(Qb, (ushort*)(ws + 12*HS), qk);
  k_softmax<<<12288, 256, 0, stream>>>(qk, probs);
  // P.V -> attt[bc][q][h]
  mgemm<2><<<dim3(2, 4, 96), 256, 0, stream>>>(probs, Vb, attt);
  // o-proj + residual in place into h0
  mgemm<3><<<dim3(4, 8, 24), 256, 0, stream>>>(pwbo, attt, (void*)h0);
  // FFN (MFMA implicit GEMM)
  k_pack<<<1, 256, 0, stream>>>(c1_w, c2_w, Wp1, Wp2);
  k_ln_b<<<dim3(8, 24), 256, 0, stream>>>(h0, ln2_w, ln2_b, lnb_b);
  k_c1m<<<dim3(4, 128, 2), 256, 0, stream>>>(lnb_b, Wp1, c1_b, tcl);
  k_c2m<<<dim3(4, 128, 2), 256, 0, stream>>>(tcl, Wp2, c2_b, h0, out0, out1);
  k_copyx<<<3072, 256, 0, stream>>>(x, out0);
}

// Round 6
// 1196.854 us; speedup vs baseline: 2.6461x; 1.0022x over previous
//
#include <hip/hip_runtime.h>
#include <math.h>

static constexpr int FEAT = 1024;
static constexpr int WDIM = 512;
static constexpr size_t PL = (size_t)FEAT * WDIM;      // 524288 per (b,c) plane
static constexpr size_t NB = (size_t)2 * 12 * PL;      // 12582912 full tensor
static constexpr size_t HS = NB / 2;                   // floats per half-slot

typedef __attribute__((ext_vector_type(8))) short bf8_t;   // 8 bf16 (4 VGPR)
typedef __attribute__((ext_vector_type(4))) float f4_t;

__device__ __forceinline__ ushort f2b(float f) {
  union { float f; unsigned u; } x; x.f = f;
  unsigned u = x.u;
  return (ushort)((u + 0x7FFFu + ((u >> 16) & 1u)) >> 16);   // RNE
}

#define GLL16(g, l) __builtin_amdgcn_global_load_lds(                         \
    (const __attribute__((address_space(1))) void*)(g),                       \
    (__attribute__((address_space(3))) void*)(l), 16, 0, 0)

// ---------------- embed: 1x1 conv 3->12 ----------------
__global__ __launch_bounds__(256)
void k_embed(const float* __restrict__ x, const float* __restrict__ ew,
             const float* __restrict__ eb, float* __restrict__ h0)
{
  int t = blockIdx.x * 256 + threadIdx.x;      // 2*1024*128
  int x4 = (t & 127) * 4;
  int y  = (t >> 7) & 1023;
  int b  = t >> 17;
  float4 xi0 = *(const float4*)&x[(((size_t)b*3+0)*FEAT + y)*WDIM + x4];
  float4 xi1 = *(const float4*)&x[(((size_t)b*3+1)*FEAT + y)*WDIM + x4];
  float4 xi2 = *(const float4*)&x[(((size_t)b*3+2)*FEAT + y)*WDIM + x4];
  #pragma unroll
  for (int c = 0; c < 12; c++) {
    float w0 = ew[c*3], w1 = ew[c*3+1], w2 = ew[c*3+2], bb = eb[c];
    float4 o;
    o.x = fmaf(xi0.x, w0, fmaf(xi1.x, w1, fmaf(xi2.x, w2, bb)));
    o.y = fmaf(xi0.y, w0, fmaf(xi1.y, w1, fmaf(xi2.y, w2, bb)));
    o.z = fmaf(xi0.z, w0, fmaf(xi1.z, w1, fmaf(xi2.z, w2, bb)));
    o.w = fmaf(xi0.w, w0, fmaf(xi1.w, w1, fmaf(xi2.w, w2, bb)));
    *(float4*)&h0[(((size_t)b*12+c)*FEAT + y)*WDIM + x4] = o;
  }
}

// ---------------- layernorm over feature axis (h), per (b,c,w), fp32 out ----------------
__global__ __launch_bounds__(256)
void k_ln(const float* __restrict__ in, const float* __restrict__ w,
          const float* __restrict__ bia, float* __restrict__ out)
{
  int bc = blockIdx.y; int c = bc % 12;
  int w0 = blockIdx.x * 64;
  int tx = threadIdx.x & 63, ty = threadIdx.x >> 6;   // 64 x 4
  const float* base = in + (size_t)bc*PL + w0;
  float s = 0.f, ss = 0.f;
  for (int h = ty; h < FEAT; h += 4) {
    float v = base[(size_t)h*WDIM + tx];
    s += v; ss = fmaf(v, v, ss);
  }
  __shared__ float S1[4][64], S2[4][64];
  S1[ty][tx] = s; S2[ty][tx] = ss;
  __syncthreads();
  if (ty == 0) {
    float t1 = S1[0][tx]+S1[1][tx]+S1[2][tx]+S1[3][tx];
    float t2 = S2[0][tx]+S2[1][tx]+S2[2][tx]+S2[3][tx];
    float mu = t1 * (1.0f/1024.0f);
    float var = t2 * (1.0f/1024.0f) - mu*mu;
    S1[0][tx] = mu; S2[0][tx] = rsqrtf(var + 1e-8f);
  }
  __syncthreads();
  float mu = S1[0][tx], ri = S2[0][tx];
  float* ob = out + (size_t)bc*PL + w0;
  for (int h = ty; h < FEAT; h += 4) {
    float v = base[(size_t)h*WDIM + tx];
    ob[(size_t)h*WDIM + tx] = (v - mu) * ri * w[c*FEAT + h] + bia[c*FEAT + h];
  }
}

// ---------------- layernorm variant: bf16 planar out (feeds conv1) ----------------
__global__ __launch_bounds__(256)
void k_ln_b(const float* __restrict__ in, const float* __restrict__ w,
            const float* __restrict__ bia, ushort* __restrict__ out)
{
  int bc = blockIdx.y; int c = bc % 12;
  int w0 = blockIdx.x * 64;
  int tx = threadIdx.x & 63, ty = threadIdx.x >> 6;
  const float* base = in + (size_t)bc*PL + w0;
  float s = 0.f, ss = 0.f;
  for (int h = ty; h < FEAT; h += 4) {
    float v = base[(size_t)h*WDIM + tx];
    s += v; ss = fmaf(v, v, ss);
  }
  __shared__ float S1[4][64], S2[4][64];
  S1[ty][tx] = s; S2[ty][tx] = ss;
  __syncthreads();
  if (ty == 0) {
    float t1 = S1[0][tx]+S1[1][tx]+S1[2][tx]+S1[3][tx];
    float t2 = S2[0][tx]+S2[1][tx]+S2[2][tx]+S2[3][tx];
    float mu = t1 * (1.0f/1024.0f);
    float var = t2 * (1.0f/1024.0f) - mu*mu;
    S1[0][tx] = mu; S2[0][tx] = rsqrtf(var + 1e-8f);
  }
  __syncthreads();
  float mu = S1[0][tx], ri = S2[0][tx];
  ushort* ob = out + (size_t)bc*PL + w0;
  for (int h = ty; h < FEAT; h += 4) {
    float v = base[(size_t)h*WDIM + tx];
    ob[(size_t)h*WDIM + tx] = f2b((v - mu) * ri * w[c*FEAT + h] + bia[c*FEAT + h]);
  }
}

// ---------------- RoPE cos/sin table: tab[w][p] = (cos, sin), w<512, p<128 ----------------
__global__ __launch_bounds__(256)
void k_rtab(float2* __restrict__ tab)
{
  int t = blockIdx.x * 256 + threadIdx.x;   // 65536
  int w = t >> 7, p = t & 127;
  float ang = (float)w * expf(-(float)p * 0.07195578432833848f);  // 10000^(-p/128)
  float s, c; sincosf(ang, &s, &c);
  tab[t] = make_float2(c, s);
}

// ---------------- fused 9x9 depthwise conv (q,k,v) + transpose + bf16 ----------------
__global__ __launch_bounds__(256)
void k_dw3t(const float* __restrict__ in, const float* __restrict__ wq,
            const float* __restrict__ wk, const float* __restrict__ wvv,
            ushort* __restrict__ oq, ushort* __restrict__ ok2, ushort* __restrict__ ov)
{
  __shared__ float tile[72*72];       // reused as ushort T[64][72] for transpose
  __shared__ float wsm[3][81];
  const int bc = blockIdx.z, c = bc % 12;
  const int y0 = blockIdx.y * 64, x0 = blockIdx.x * 64;
  const int tid = threadIdx.x, lane = tid & 63, wv_ = tid >> 6;
  const float* base = in + (size_t)bc*PL;

  for (int i = tid; i < 1296; i += 256) {
    int r = i / 18, c4 = (i % 18) * 4;
    int gy = y0 - 4 + r, gx = x0 - 4 + c4;
    float4 v = {0.f,0.f,0.f,0.f};
    if ((unsigned)gy < 1024u && (unsigned)gx < 512u)
      v = *(const float4*)&base[(size_t)gy*512 + gx];
    *(float4*)&tile[r*72 + c4] = v;
  }
  if (tid < 81) { wsm[0][tid] = wq[c*81+tid]; wsm[1][tid] = wk[c*81+tid]; wsm[2][tid] = wvv[c*81+tid]; }
  __syncthreads();

  float aq[16] = {}, ak[16] = {}, av[16] = {};
  #pragma unroll 1
  for (int dx = 0; dx < 9; dx++) {
    float wq9[9], wk9[9], wv9[9];
    #pragma unroll
    for (int dy = 0; dy < 9; dy++) {
      wq9[dy] = wsm[0][dy*9+dx]; wk9[dy] = wsm[1][dy*9+dx]; wv9[dy] = wsm[2][dy*9+dx];
    }
    const float* col = &tile[(wv_*16)*72 + lane + dx];
    #pragma unroll
    for (int r = 0; r < 24; r++) {
      float v = col[r*72];
      int dylo = (r > 15) ? (r - 15) : 0;
      int dyhi = (r < 8) ? r : 8;
      #pragma unroll
      for (int dy = 0; dy < 9; dy++) {
        if (dy >= dylo && dy <= dyhi) {
          aq[r-dy] = fmaf(v, wq9[dy], aq[r-dy]);
          ak[r-dy] = fmaf(v, wk9[dy], ak[r-dy]);
          av[r-dy] = fmaf(v, wv9[dy], av[r-dy]);
        }
      }
    }
  }

  ushort* T = (ushort*)tile;
#define DW_EMIT(ACC, OUT)                                                     \
  {                                                                           \
    __syncthreads();                                                          \
    uint pk[8];                                                               \
    _Pragma("unroll")                                                         \
    for (int u = 0; u < 8; u++)                                               \
      pk[u] = (uint)f2b(ACC[2*u]) | ((uint)f2b(ACC[2*u+1]) << 16);            \
    uint4* dst = (uint4*)&T[lane*72 + wv_*16];                                \
    dst[0] = make_uint4(pk[0],pk[1],pk[2],pk[3]);                             \
    dst[1] = make_uint4(pk[4],pk[5],pk[6],pk[7]);                             \
    __syncthreads();                                                          \
    ushort* op = OUT + (size_t)bc*PL;                                         \
    _Pragma("unroll")                                                         \
    for (int it = 0; it < 2; it++) {                                          \
      int idx = it*256 + tid;                                                 \
      int xr = idx >> 3, y8 = (idx & 7) * 8;                                  \
      uint4 vv = *(uint4*)&T[xr*72 + y8];                                     \
      *(uint4*)&op[(size_t)(x0+xr)*1024 + y0 + y8] = vv;                      \
    }                                                                         \
  }
  DW_EMIT(aq, oq)
  DW_EMIT(ak, ok2)
  DW_EMIT(av, ov)
#undef DW_EMIT
}

// ---------------- fp32 -> bf16 convert, 4 tensors (outs contiguous) ----------------
__global__ __launch_bounds__(256)
void k_cvt4(const float* __restrict__ p0, const float* __restrict__ p1,
            const float* __restrict__ p2, const float* __restrict__ p3,
            ushort* __restrict__ out)
{
  const float* ins[4] = {p0, p1, p2, p3};
  const float* in = ins[blockIdx.y];
  size_t i = ((size_t)blockIdx.x * 256 + threadIdx.x) * 8;
  ushort* o = out + (size_t)blockIdx.y * NB + i;
  float4 v0 = *(const float4*)&in[i];
  float4 v1 = *(const float4*)&in[i+4];
  union { ushort u[8]; uint4 v; } t;
  t.u[0]=f2b(v0.x); t.u[1]=f2b(v0.y); t.u[2]=f2b(v0.z); t.u[3]=f2b(v0.w);
  t.u[4]=f2b(v1.x); t.u[5]=f2b(v1.y); t.u[6]=f2b(v1.z); t.u[7]=f2b(v1.w);
  *(uint4*)o = t.v;
}

// ---------------- row softmax (rows of 512), one wave per row, bf16 out ----------------
__global__ __launch_bounds__(256)
void k_softmax(const float* __restrict__ qk, ushort* __restrict__ probs)
{
  int wave = threadIdx.x >> 6, lane = threadIdx.x & 63;
  size_t row = (size_t)blockIdx.x * 4 + wave;
  const float* r = qk + row * 512;
  float v[8];
  float m = -1e30f;
  #pragma unroll
  for (int j = 0; j < 8; j++) { v[j] = r[lane + 64*j]; m = fmaxf(m, v[j]); }
  #pragma unroll
  for (int o = 32; o; o >>= 1) m = fmaxf(m, __shfl_xor(m, o));
  float s = 0.f;
  #pragma unroll
  for (int j = 0; j < 8; j++) { v[j] = expf(v[j] - m); s += v[j]; }
  #pragma unroll
  for (int o = 32; o; o >>= 1) s += __shfl_xor(s, o);
  float inv = 1.0f / s;
  ushort* p = probs + row * 512;
  #pragma unroll
  for (int j = 0; j < 8; j++) p[lane + 64*j] = f2b(v[j] * inv);
}

// ---------------- MFMA bf16 GEMM, fragment-ordered LDS, 128x128 tile, BK=64 ----------------
// MODE 0: QKV proj, z = t*96 + zz, t=0:Q(+rope) 1:K(+rope) 2:V. Tensors contiguous at t*NB.
// MODE 1: QK^T/32 -> qk fp32. MODE 2: PV -> attt. MODE 3: OPROJ += into h0 (fp32).
template<int MODE>
__global__ __launch_bounds__(256)
void mgemm(const ushort* __restrict__ Ab, const ushort* __restrict__ Bb,
           void* __restrict__ Cb, const float2* __restrict__ rtab)
{
  constexpr int K   = (MODE==1) ? 256 : ((MODE==2) ? 512 : 1024);
  constexpr int LDA = (MODE==1) ? 256 : ((MODE==2) ? 512 : 1024);
  constexpr int LDB = LDA;

  const int z = blockIdx.z;
  const ushort* A; const ushort* B;
  int zz = z, t = 0; size_t toff = 0;
  if constexpr (MODE==0) {
    t = z / 96; zz = z - 96*t; toff = (size_t)t * NB;
    int bc = zz >> 2, head = zz & 3, c = bc % 12;
    A = Ab + toff + ((size_t)c*1024 + head*256)*1024;
    B = Bb + toff + (size_t)bc*524288;
  } else if constexpr (MODE==1) {
    A = Ab + (size_t)z*131072; B = Bb + (size_t)z*131072;
  } else if constexpr (MODE==2) {
    A = Ab + (size_t)z*262144; B = Bb + (size_t)z*131072;
  } else {
    int c = z % 12;
    A = Ab + (size_t)c*1048576;
    B = Bb + (size_t)z*524288;
  }

  const int m0 = blockIdx.y * 128, n0 = blockIdx.x * 128;
  const int tid = threadIdx.x, lane = tid & 63, wv = tid >> 6;
  const int wr = wv >> 1, wc = wv & 1;
  const int lm = lane & 15, lg = lane >> 4;

  __shared__ __align__(16) ushort Alds[8192];   // 16 slots x 512: slot = mfrag*2 + khalf
  __shared__ __align__(16) ushort Blds[8192];

  // wave wv stages slots 4wv..4wv+3 of each operand
  const ushort* gA[4]; const ushort* gB[4];
  ushort* lA[4]; ushort* lB[4];
  #pragma unroll
  for (int sl = 0; sl < 4; sl++) {
    int mf = 2*wv + (sl >> 1), kh = sl & 1;
    gA[sl] = A + (size_t)(m0 + mf*16 + lm)*LDA + kh*32 + 8*lg;
    gB[sl] = B + (size_t)(n0 + mf*16 + lm)*LDB + kh*32 + 8*lg;
    lA[sl] = &Alds[(mf*2 + kh)*512];
    lB[sl] = &Blds[(mf*2 + kh)*512];
  }

  f4_t acc[4][4];
  #pragma unroll
  for (int i = 0; i < 4; i++)
    #pragma unroll
    for (int j = 0; j < 4; j++) acc[i][j] = (f4_t){0.f, 0.f, 0.f, 0.f};

  for (int k0 = 0; k0 < K; k0 += 64) {
    #pragma unroll
    for (int sl = 0; sl < 4; sl++) { GLL16(gA[sl] + k0, lA[sl]); GLL16(gB[sl] + k0, lB[sl]); }
    __syncthreads();
    #pragma unroll
    for (int kk = 0; kk < 2; kk++) {
      bf8_t fa[4], fb[4];
      #pragma unroll
      for (int i = 0; i < 4; i++)
        fa[i] = *(const bf8_t*)&Alds[(((wr*4+i)<<1) + kk)*512 + lane*8];
      #pragma unroll
      for (int j = 0; j < 4; j++)
        fb[j] = *(const bf8_t*)&Blds[(((wc*4+j)<<1) + kk)*512 + lane*8];
      #pragma unroll
      for (int i = 0; i < 4; i++)
        #pragma unroll
        for (int j = 0; j < 4; j++)
          acc[i][j] = __builtin_amdgcn_mfma_f32_16x16x32_bf16(fa[i], fb[j], acc[i][j], 0, 0, 0);
    }
    __syncthreads();
  }

  // D fragment: col = lane&15, row = (lane>>4)*4 + reg
  if constexpr (MODE==0) {
    ushort* C = (ushort*)Cb + toff + (size_t)zz*131072;
    if (t < 2) {                    // Qb/Kb [zz][w][d] + RoPE from table
      #pragma unroll
      for (int j = 0; j < 4; j++) {
        int w = n0 + wc*64 + j*16 + lm;
        #pragma unroll
        for (int i = 0; i < 4; i++) {
          int d0 = m0 + wr*64 + i*16 + lg*4;
          int p0 = d0 >> 1;
          float2 cs0 = rtab[w*128 + p0];
          float2 cs1 = rtab[w*128 + p0 + 1];
          f4_t a = acc[i][j];
          ushort4 o;
          o.x = f2b(a.x*cs0.x - a.y*cs0.y);
          o.y = f2b(a.y*cs0.x + a.x*cs0.y);
          o.z = f2b(a.z*cs1.x - a.w*cs1.y);
          o.w = f2b(a.w*cs1.x + a.z*cs1.y);
          *(ushort4*)&C[(size_t)w*256 + d0] = o;
        }
      }
    } else {                        // Vb [zz][d][w]
      #pragma unroll
      for (int i = 0; i < 4; i++) {
        int d0 = m0 + wr*64 + i*16 + lg*4;
        #pragma unroll
        for (int j = 0; j < 4; j++) {
          int w = n0 + wc*64 + j*16 + lm;
          f4_t a = acc[i][j];
          C[(size_t)(d0+0)*512 + w] = f2b(a.x);
          C[(size_t)(d0+1)*512 + w] = f2b(a.y);
          C[(size_t)(d0+2)*512 + w] = f2b(a.z);
          C[(size_t)(d0+3)*512 + w] = f2b(a.w);
        }
      }
    }
  } else if constexpr (MODE==1) {   // qk fp32, *1/32
    float* C = (float*)Cb + (size_t)z*262144;
    #pragma unroll
    for (int i = 0; i < 4; i++) {
      int q0 = m0 + wr*64 + i*16 + lg*4;
      #pragma unroll
      for (int j = 0; j < 4; j++) {
        int kc = n0 + wc*64 + j*16 + lm;
        f4_t a = acc[i][j];
        C[(size_t)(q0+0)*512 + kc] = a.x * 0.03125f;
        C[(size_t)(q0+1)*512 + kc] = a.y * 0.03125f;
        C[(size_t)(q0+2)*512 + kc] = a.z * 0.03125f;
        C[(size_t)(q0+3)*512 + kc] = a.w * 0.03125f;
      }
    }
  } else if constexpr (MODE==2) {   // attt[bc][q][head*256+d]
    ushort* C = (ushort*)Cb + (size_t)(z>>2)*524288 + (size_t)(z&3)*256;
    #pragma unroll
    for (int i = 0; i < 4; i++) {
      int q0 = m0 + wr*64 + i*16 + lg*4;
      #pragma unroll
      for (int j = 0; j < 4; j++) {
        int d = n0 + wc*64 + j*16 + lm;
        f4_t a = acc[i][j];
        C[(size_t)(q0+0)*1024 + d] = f2b(a.x);
        C[(size_t)(q0+1)*1024 + d] = f2b(a.y);
        C[(size_t)(q0+2)*1024 + d] = f2b(a.z);
        C[(size_t)(q0+3)*1024 + d] = f2b(a.w);
      }
    }
  } else {                          // MODE3: h0 += , fp32 in place
    float* C = (float*)Cb + (size_t)z*524288;
    #pragma unroll
    for (int i = 0; i < 4; i++) {
      int f0 = m0 + wr*64 + i*16 + lg*4;
      #pragma unroll
      for (int j = 0; j < 4; j++) {
        int w = n0 + wc*64 + j*16 + lm;
        f4_t a = acc[i][j];
        C[(size_t)(f0+0)*512 + w] += a.x;
        C[(size_t)(f0+1)*512 + w] += a.y;
        C[(size_t)(f0+2)*512 + w] += a.z;
        C[(size_t)(f0+3)*512 + w] += a.w;
      }
    }
  }
}

// ---------------- pack FFN conv weights to MFMA layouts (bf16, zero-padded) ----------------
__global__ __launch_bounds__(256)
void k_pack(const float* __restrict__ c1w, const float* __restrict__ c2w,
            ushort* __restrict__ wp1, ushort* __restrict__ wp2)
{
  int tid = threadIdx.x;
  for (int i = tid; i < 48*168; i += 256) {
    int oc = i / 168, k = i % 168;
    ushort v = 0;
    if (k < 160) {
      int ofs = k >> 4, ch = k & 15;
      if (ofs < 9 && ch < 12) v = f2b(c1w[(oc*12 + ch)*9 + ofs]);
    }
    wp1[i] = v;
  }
  for (int i = tid; i < 16*584; i += 256) {
    int oc = i / 584, k = i % 584;
    ushort v = 0;
    if (k < 576) {
      int ofs = k >> 6, ch = k & 63;
      if (oc < 12 && ch < 48) v = f2b(c2w[(oc*48 + ch)*9 + ofs]);
    }
    wp2[i] = v;
  }
}

// ---------------- conv1 MFMA: 3x3 12->48, relu^2, bf16 channel-last out ----------------
__global__ __launch_bounds__(256)
void k_c1m(const ushort* __restrict__ in, const ushort* __restrict__ Wp,
           const float* __restrict__ bias, ushort* __restrict__ out)
{
  __shared__ __align__(16) ushort Wl[48*168];
  __shared__ __align__(16) ushort Xl[4*136*16];
  __shared__ float Bs[48];
  const int b = blockIdx.z, ybase = blockIdx.y*8, x0 = blockIdx.x*128;
  const int tid = threadIdx.x, lane = tid & 63, wv = tid >> 6;
  const int lm = lane & 15, lg = lane >> 4;
  const int hl = lg >> 1, cbs = lg & 1;

  for (int i = tid; i < 48*168; i += 256) Wl[i] = Wp[i];
  for (int i = tid; i < 4*136*16; i += 256) Xl[i] = 0;
  if (tid < 48) Bs[tid] = bias[tid];

  for (int y8 = 0; y8 < 8; y8++) {
    int y = ybase + y8;
    __syncthreads();
    for (int i = tid; i < 3*34*12; i += 256) {
      int ch = i % 12, cc = (i/12) % 34, r = i/(12*34);
      int sy = y + r - 1, sx = x0 - 4 + cc*4;
      ushort4 v = (ushort4){0,0,0,0};
      if ((unsigned)sy < 1024u) {
        const ushort* p = in + ((size_t)(b*12+ch)*1024 + sy)*512 + sx;
        if (sx >= 0 && sx <= 508) v = *(const ushort4*)p;
        else {
          ushort tv[4] = {0,0,0,0};
          #pragma unroll
          for (int u = 0; u < 4; u++) { int xx = sx+u; if ((unsigned)xx < 512u) tv[u] = p[u]; }
          v = (ushort4){tv[0],tv[1],tv[2],tv[3]};
        }
      }
      int cb = ch >> 3, ce = ch & 7;
      #pragma unroll
      for (int u = 0; u < 4; u++) {
        int col = cc*4 + u;
        Xl[((r*136 + col) << 4) + ((cb ^ (col & 1)) << 3) + ce] = ((const ushort*)&v)[u];
      }
    }
    __syncthreads();

    f4_t acc[3][2];
    #pragma unroll
    for (int i = 0; i < 3; i++) { acc[i][0] = (f4_t){0,0,0,0}; acc[i][1] = (f4_t){0,0,0,0}; }
    #pragma unroll
    for (int s = 0; s < 5; s++) {
      bf8_t af[3];
      #pragma unroll
      for (int mf = 0; mf < 3; mf++)
        af[mf] = *(const bf8_t*)&Wl[(mf*16 + lm)*168 + s*32 + lg*8];
      int ofs = 2*s + hl;
      int dy = ofs / 3, dx = ofs - dy*3;
      #pragma unroll
      for (int nf = 0; nf < 2; nf++) {
        int col = (wv*2 + nf)*16 + lm + dx + 3;
        bf8_t bf = *(const bf8_t*)&Xl[((dy*136 + col) << 4) + ((cbs ^ (col & 1)) << 3)];
        #pragma unroll
        for (int mf = 0; mf < 3; mf++)
          acc[mf][nf] = __builtin_amdgcn_mfma_f32_16x16x32_bf16(af[mf], bf, acc[mf][nf], 0, 0, 0);
      }
    }
    #pragma unroll
    for (int nf = 0; nf < 2; nf++) {
      int p = (wv*2 + nf)*16 + lm;
      ushort* op = out + (((size_t)(b*1024 + y)*512) + x0 + p)*48;
      #pragma unroll
      for (int mf = 0; mf < 3; mf++) {
        int oc0 = mf*16 + lg*4;
        f4_t a = acc[mf][nf];
        float r0 = fmaxf(a.x + Bs[oc0+0], 0.f);
        float r1 = fmaxf(a.y + Bs[oc0+1], 0.f);
        float r2 = fmaxf(a.z + Bs[oc0+2], 0.f);
        float r3 = fmaxf(a.w + Bs[oc0+3], 0.f);
        ushort4 o;
        o.x = f2b(r0*r0); o.y = f2b(r1*r1); o.z = f2b(r2*r2); o.w = f2b(r3*r3);
        *(ushort4*)&op[oc0] = o;
      }
    }
  }
}

// ---------------- conv2 MFMA: 3x3 48->12, +bias +residual, dual planar fp32 out ----------------
__global__ __launch_bounds__(256)
void k_c2m(const ushort* __restrict__ tin, const ushort* __restrict__ Wp,
           const float* __restrict__ bias, const float* __restrict__ h1,
           float* __restrict__ out0, float* __restrict__ out1)
{
  __shared__ __align__(16) ushort Wl[16*584];
  __shared__ __align__(16) ushort Xl[3*132*64];
  __shared__ float Bs[12];
  const int b = blockIdx.z, ybase = blockIdx.y*8, x0 = blockIdx.x*128;
  const int tid = threadIdx.x, lane = tid & 63, wv = tid >> 6;
  const int lm = lane & 15, lg = lane >> 4;

  for (int i = tid; i < 16*584; i += 256) Wl[i] = Wp[i];
  for (int i = tid; i < 3*132*64; i += 256) Xl[i] = 0;
  if (tid < 12) Bs[tid] = bias[tid];

  for (int y8 = 0; y8 < 8; y8++) {
    int y = ybase + y8;
    __syncthreads();
    for (int i = tid; i < 3*132*6; i += 256) {
      int ck = i % 6, col = (i/6) % 132, r = i/(6*132);
      int sy = y + r - 1, sx = x0 + col - 1;
      uint4 v = (uint4){0u,0u,0u,0u};
      if ((unsigned)sy < 1024u && (unsigned)sx < 512u)
        v = *(const uint4*)&tin[(((size_t)(b*1024 + sy)*512 + sx)*48) + ck*8];
      *(uint4*)&Xl[((r*132 + col) << 6) + ((ck ^ (col & 7)) << 3)] = v;
    }
    __syncthreads();

    f4_t acc[2];
    acc[0] = (f4_t){0,0,0,0}; acc[1] = (f4_t){0,0,0,0};
    #pragma unroll
    for (int s = 0; s < 18; s++) {
      bf8_t af = *(const bf8_t*)&Wl[lm*584 + s*32 + lg*8];
      int ofs = s >> 1;
      int dy = ofs / 3, dx = ofs - dy*3;
      int cb = ((s & 1) << 2) + lg;
      #pragma unroll
      for (int nf = 0; nf < 2; nf++) {
        int col = (wv*2 + nf)*16 + lm + dx;
        bf8_t bf = *(const bf8_t*)&Xl[((dy*132 + col) << 6) + ((cb ^ (col & 7)) << 3)];
        acc[nf] = __builtin_amdgcn_mfma_f32_16x16x32_bf16(af, bf, acc[nf], 0, 0, 0);
      }
    }
    if (lg < 3) {
      #pragma unroll
      for (int nf = 0; nf < 2; nf++) {
        int p = x0 + (wv*2 + nf)*16 + lm;
        f4_t a = acc[nf];
        #pragma unroll
        for (int r = 0; r < 4; r++) {
          int oc = lg*4 + r;
          size_t po = ((size_t)(b*12 + oc)*1024 + y)*512 + p;
          float hv = a[r] + Bs[oc] + h1[po];
          out1[po] = hv;
          out0[((size_t)(b*15 + 3 + oc)*1024 + y)*512 + p] = hv;
        }
      }
    }
  }
}

// ---------------- copy x into out0 channels 0..2 ----------------
__global__ __launch_bounds__(256)
void k_copyx(const float* __restrict__ x, float* __restrict__ out0)
{
  int t = blockIdx.x * 256 + threadIdx.x;
  int x4 = (t & 127) * 4;
  int y  = (t >> 7) & 1023;
  int ci = (t >> 17) % 3;
  int b  = t / 393216;
  *(float4*)&out0[(((size_t)b*15 + ci)*FEAT + y)*WDIM + x4] =
      *(const float4*)&x[(((size_t)b*3 + ci)*FEAT + y)*WDIM + x4];
}

extern "C" void kernel_launch(void* const* d_in, const int* in_sizes, int n_in,
                              void* d_out, int out_size, void* d_ws, size_t ws_size,
                              hipStream_t stream)
{
  const float* x       = (const float*)d_in[0];
  const float* embed_w = (const float*)d_in[1];
  const float* embed_b = (const float*)d_in[2];
  const float* ln1_w   = (const float*)d_in[3];
  const float* ln1_b   = (const float*)d_in[4];
  const float* q_dw    = (const float*)d_in[5];
  const float* q_pw    = (const float*)d_in[6];
  const float* k_dw    = (const float*)d_in[7];
  const float* k_pw    = (const float*)d_in[8];
  const float* v_dw    = (const float*)d_in[9];
  const float* v_pw    = (const float*)d_in[10];
  const float* o_pw    = (const float*)d_in[11];
  const float* ln2_w   = (const float*)d_in[12];
  const float* ln2_b   = (const float*)d_in[13];
  const float* c1_w    = (const float*)d_in[14];
  const float* c1_b    = (const float*)d_in[15];
  const float* c2_w    = (const float*)d_in[16];
  const float* c2_b    = (const float*)d_in[17];

  // Half-slot map (HS floats each):
  //   H0,H1 h0 | H2,H3 lnb (later lnb_b bf16 in H2) | H4 dwtq->probs.lo->Wp
  //   H5 dwtk->probs.hi | H6 dwtv->attt | H7..H10 pwbq,pwbk,pwbv,pwbo->tcl
  //   H11 Qb | H12 Kb | H13 Vb   (Qb,Kb,Vb contiguous; pwb q,k,v,o contiguous;
  //   dwt q,k,v contiguous -> single merged proj launch)
  float* ws = (float*)d_ws;
  float*  h0   = ws + 0*HS;
  float*  lnb  = ws + 2*HS;
  ushort* dwtq = (ushort*)(ws + 4*HS);
  ushort* dwtk = (ushort*)(ws + 5*HS);
  ushort* dwtv = (ushort*)(ws + 6*HS);
  ushort* pwbq = (ushort*)(ws + 7*HS);
  ushort* pwbo = (ushort*)(ws + 10*HS);
  ushort* Qb   = (ushort*)(ws + 11*HS);
  ushort* Kb   = (ushort*)(ws + 12*HS);
  ushort* Vb   = (ushort*)(ws + 13*HS);
  ushort* probs= (ushort*)(ws + 4*HS);
  ushort* attt = (ushort*)(ws + 6*HS);
  ushort* Wp1  = (ushort*)(ws + 4*HS);
  ushort* Wp2  = Wp1 + 48*168;
  ushort* lnb_b= (ushort*)(ws + 2*HS);
  ushort* tcl  = (ushort*)(ws + 7*HS);

  float* out0 = (float*)d_out;                       // (2,15,1024,512)
  float* out1 = out0 + (size_t)2*15*FEAT*WDIM;       // (2,12,1024,512)
  float* qk   = out1 + NB;                           // (2,12,4,512,512)
  // RoPE table lives in the (not-yet-written) prefix of qk: 65536 float2 = 512 KB.
  float2* rtab = (float2*)qk;

  k_rtab<<<256, 256, 0, stream>>>(rtab);
  k_embed<<<1024, 256, 0, stream>>>(x, embed_w, embed_b, h0);
  k_ln<<<dim3(8, 24), 256, 0, stream>>>(h0, ln1_w, ln1_b, lnb);
  // fused depthwise 9x9 + transpose + bf16
  k_dw3t<<<dim3(8, 16, 24), 256, 0, stream>>>(lnb, q_dw, k_dw, v_dw, dwtq, dwtk, dwtv);
  // pw weights -> bf16 (4 tensors, contiguous outputs)
  k_cvt4<<<dim3(6144, 4), 256, 0, stream>>>(q_pw, k_pw, v_pw, o_pw, pwbq);
  // Q, K (RoPE fused via table) and V projections in ONE launch
  mgemm<0><<<dim3(4, 2, 288), 256, 0, stream>>>(pwbq, dwtq, Qb, rtab);
  // QK^T / 32 -> qk output (fp32) — overwrites rtab region, which is now dead
  mgemm<1><<<dim3(4, 4, 96), 256, 0, stream>>>(Qb, Kb, qk, nullptr);
  k_softmax<<<12288, 256, 0, stream>>>(qk, probs);
  // P.V -> attt[bc][q][h]
  mgemm<2><<<dim3(2, 4, 96), 256, 0, stream>>>(probs, Vb, attt, nullptr);
  // o-proj + residual in place into h0
  mgemm<3><<<dim3(4, 8, 24), 256, 0, stream>>>(pwbo, attt, (void*)h0, nullptr);
  // FFN (MFMA implicit GEMM)
  k_pack<<<1, 256, 0, stream>>>(c1_w, c2_w, Wp1, Wp2);
  k_ln_b<<<dim3(8, 24), 256, 0, stream>>>(h0, ln2_w, ln2_b, lnb_b);
  k_c1m<<<dim3(4, 128, 2), 256, 0, stream>>>(lnb_b, Wp1, c1_b, tcl);
  k_c2m<<<dim3(4, 128, 2), 256, 0, stream>>>(tcl, Wp2, c2_b, h0, out0, out1);
  k_copyx<<<3072, 256, 0, stream>>>(x, out0);
}